// Round 1
// baseline (1406.662 us; speedup 1.0000x reference)
//
#include <hip/hip_runtime.h>
#include <math.h>

#define NB 8192
#define NHID 256

// =====================================================================
// K1: per-modality Linear -> ReLU -> LayerNorm, writes seq[(b*3+m)][256]
// block = 256 thr, tile 32 rows x 256 cols (full row needed for LN)
// =====================================================================
__global__ __launch_bounds__(256) void proj_ln_kernel(
    const float* __restrict__ x0, const float* __restrict__ Wp0, const float* __restrict__ bp0,
    const float* __restrict__ g0, const float* __restrict__ be0,
    const float* __restrict__ x1, const float* __restrict__ Wp1, const float* __restrict__ bp1,
    const float* __restrict__ g1, const float* __restrict__ be1,
    const float* __restrict__ x2, const float* __restrict__ Wp2, const float* __restrict__ bp2,
    const float* __restrict__ g2, const float* __restrict__ be2,
    float* __restrict__ seq)
{
    const int m = blockIdx.y;
    const float* x; const float* Wp; const float* bp; const float* g; const float* be; int d;
    if (m == 0)      { x = x0; Wp = Wp0; bp = bp0; g = g0; be = be0; d = 512; }
    else if (m == 1) { x = x1; Wp = Wp1; bp = bp1; g = g1; be = be1; d = 768; }
    else             { x = x2; Wp = Wp2; bp = bp2; g = g2; be = be2; d = 1024; }

    __shared__ float As[16][32];    // A transposed: As[k][row]
    __shared__ float Bs[16][256];   // Bs[k][col]

    const int tid = threadIdx.x;
    const int tx = tid & 63;        // 64 col-threads * 4 cols
    const int ty = tid >> 6;        // 4 row-threads  * 8 rows
    const int r0 = blockIdx.x * 32;

    float acc[8][4];
#pragma unroll
    for (int r = 0; r < 8; r++)
#pragma unroll
        for (int c = 0; c < 4; c++) acc[r][c] = 0.f;

    for (int k0 = 0; k0 < d; k0 += 16) {
        __syncthreads();
        // stage A: 32 rows x 16 k (2 elems/thread), transposed
        {
            int eid = tid * 2;
            int row = eid >> 4, kk = eid & 15;
            float2 v = *(const float2*)&x[(size_t)(r0 + row) * d + k0 + kk];
            As[kk][row]     = v.x;
            As[kk + 1][row] = v.y;
        }
        // stage B: 16 x 256 (4 float4/thread)
#pragma unroll
        for (int i = 0; i < 4; i++) {
            int f4id = i * 256 + tid;
            int kk = f4id >> 6, c4 = f4id & 63;
            *(float4*)&Bs[kk][c4 * 4] =
                *(const float4*)&Wp[(size_t)(k0 + kk) * NHID + c4 * 4];
        }
        __syncthreads();
#pragma unroll
        for (int kk = 0; kk < 16; kk++) {
            float4 a0 = *(float4*)&As[kk][ty * 8];
            float4 a1 = *(float4*)&As[kk][ty * 8 + 4];
            float4 b  = *(float4*)&Bs[kk][tx * 4];
            float ar[8] = {a0.x, a0.y, a0.z, a0.w, a1.x, a1.y, a1.z, a1.w};
            float bc[4] = {b.x, b.y, b.z, b.w};
#pragma unroll
            for (int r = 0; r < 8; r++)
#pragma unroll
                for (int c = 0; c < 4; c++)
                    acc[r][c] = fmaf(ar[r], bc[c], acc[r][c]);
        }
    }

    // epilogue: bias + relu + layernorm (each wave owns its 8 rows fully)
    const int colb = tx * 4;
    float4 bpv = *(const float4*)&bp[colb];
    float4 gv  = *(const float4*)&g[colb];
    float4 bev = *(const float4*)&be[colb];
    float bpc[4] = {bpv.x, bpv.y, bpv.z, bpv.w};
    float gc[4]  = {gv.x, gv.y, gv.z, gv.w};
    float bec[4] = {bev.x, bev.y, bev.z, bev.w};

#pragma unroll
    for (int r = 0; r < 8; r++) {
        float y[4];
#pragma unroll
        for (int c = 0; c < 4; c++) y[c] = fmaxf(acc[r][c] + bpc[c], 0.f);
        float s  = y[0] + y[1] + y[2] + y[3];
        float s2 = y[0]*y[0] + y[1]*y[1] + y[2]*y[2] + y[3]*y[3];
#pragma unroll
        for (int off = 1; off < 64; off <<= 1) {
            s  += __shfl_xor(s, off);
            s2 += __shfl_xor(s2, off);
        }
        float meanv = s * (1.f / 256.f);
        float varv  = s2 * (1.f / 256.f) - meanv * meanv;
        float inv   = 1.f / sqrtf(varv + 1e-5f);
        float4 o;
        o.x = (y[0] - meanv) * inv * gc[0] + bec[0];
        o.y = (y[1] - meanv) * inv * gc[1] + bec[1];
        o.z = (y[2] - meanv) * inv * gc[2] + bec[2];
        o.w = (y[3] - meanv) * inv * gc[3] + bec[3];
        *(float4*)&seq[((size_t)(r0 + ty * 8 + r) * 3 + m) * NHID + colb] = o;
    }
}

// =====================================================================
// K2: qkv = seq[24576,256] @ Win[256,768] + bin  -> qkv[24576,768]
// 128x128 tile, 8x8 micro, BK=16
// =====================================================================
__global__ __launch_bounds__(256) void qkv_kernel(
    const float* __restrict__ seq, const float* __restrict__ Win,
    const float* __restrict__ bin, float* __restrict__ qkv)
{
    __shared__ float As[16][128];
    __shared__ float Bs[16][128];
    const int tid = threadIdx.x;
    const int tx = tid & 15, ty = tid >> 4;
    const int c0 = blockIdx.x * 128;
    const int r0 = blockIdx.y * 128;

    float acc[8][8];
#pragma unroll
    for (int r = 0; r < 8; r++)
#pragma unroll
        for (int c = 0; c < 8; c++) acc[r][c] = 0.f;

    for (int k0 = 0; k0 < 256; k0 += 16) {
        __syncthreads();
        // stage A transposed: 128 rows x 16k = 512 f4
#pragma unroll
        for (int i = 0; i < 2; i++) {
            int f4id = i * 256 + tid;
            int row = f4id >> 2, kq = (f4id & 3) << 2;
            float4 v = *(const float4*)&seq[(size_t)(r0 + row) * 256 + k0 + kq];
            As[kq + 0][row] = v.x; As[kq + 1][row] = v.y;
            As[kq + 2][row] = v.z; As[kq + 3][row] = v.w;
        }
        // stage B natural: 16k x 128 cols = 512 f4
#pragma unroll
        for (int i = 0; i < 2; i++) {
            int f4id = i * 256 + tid;
            int kk = f4id >> 5, c4 = f4id & 31;
            *(float4*)&Bs[kk][c4 * 4] =
                *(const float4*)&Win[(size_t)(k0 + kk) * 768 + c0 + c4 * 4];
        }
        __syncthreads();
#pragma unroll
        for (int kk = 0; kk < 16; kk++) {
            float4 a0 = *(float4*)&As[kk][ty * 8];
            float4 a1 = *(float4*)&As[kk][ty * 8 + 4];
            float4 b0 = *(float4*)&Bs[kk][tx * 4];
            float4 b1 = *(float4*)&Bs[kk][64 + tx * 4];
            float a[8]  = {a0.x, a0.y, a0.z, a0.w, a1.x, a1.y, a1.z, a1.w};
            float bb[8] = {b0.x, b0.y, b0.z, b0.w, b1.x, b1.y, b1.z, b1.w};
#pragma unroll
            for (int r = 0; r < 8; r++)
#pragma unroll
                for (int c = 0; c < 8; c++)
                    acc[r][c] = fmaf(a[r], bb[c], acc[r][c]);
        }
    }

    const int ca = c0 + tx * 4, cb = ca + 64;
    float4 ba  = *(const float4*)&bin[ca];
    float4 bb4 = *(const float4*)&bin[cb];
#pragma unroll
    for (int r = 0; r < 8; r++) {
        int row = r0 + ty * 8 + r;
        float4 oa = make_float4(acc[r][0] + ba.x,  acc[r][1] + ba.y,
                                acc[r][2] + ba.z,  acc[r][3] + ba.w);
        float4 ob = make_float4(acc[r][4] + bb4.x, acc[r][5] + bb4.y,
                                acc[r][6] + bb4.z, acc[r][7] + bb4.w);
        *(float4*)&qkv[(size_t)row * 768 + ca] = oa;
        *(float4*)&qkv[(size_t)row * 768 + cb] = ob;
    }
}

// =====================================================================
// K3: attention (M=3, H=4, HD=64) + out-proj + mean + edge-weight MLP
// 4 batch rows per block
// =====================================================================
__global__ __launch_bounds__(256) void attn_kernel(
    const float* __restrict__ qkv, const float* __restrict__ Wout,
    const float* __restrict__ bout, const float* __restrict__ W1,
    const float* __restrict__ b1, const float* __restrict__ W2,
    const float* __restrict__ b2, float* __restrict__ fused, float* __restrict__ ew)
{
    __shared__ float qk[4][2304];       // [b][m*768 + c] ; q|k|v at +0|+256|+512
    __shared__ float at[4][4][3][3];    // attn weights
    __shared__ float ol[12][256];       // attention output rows (b*3+s)
    __shared__ float fl[4][256];        // fused rows
    __shared__ float h1[4][128];        // MLP hidden

    const int tid = threadIdx.x;
    const int b0 = blockIdx.x * 4;

    // load qkv for 4 batches: 9216 floats = 2304 f4
#pragma unroll
    for (int i = 0; i < 9; i++) {
        int f4 = i * 256 + tid;
        int lb = f4 / 576, rem = f4 - lb * 576;
        *(float4*)&qk[lb][rem * 4] =
            *(const float4*)&qkv[(size_t)(b0 + lb) * 2304 + rem * 4];
    }
    __syncthreads();

    // scores: 4b * 4h * 3s * 3t = 144
    if (tid < 144) {
        int lb = tid / 36, r = tid % 36;
        int h = r / 9, s = (r / 3) % 3, t = r % 3;
        const float* qp = &qk[lb][s * 768 + h * 64];
        const float* kp = &qk[lb][t * 768 + 256 + h * 64];
        float sum = 0.f;
#pragma unroll
        for (int dd = 0; dd < 64; dd++) sum = fmaf(qp[dd], kp[dd], sum);
        at[lb][h][s][t] = sum * 0.125f;
    }
    __syncthreads();

    // softmax over t (3 elems) per (b,h,s)
    if (tid < 48) {
        int lb = tid / 12, h = (tid / 3) % 4, s = tid % 3;
        float v0 = at[lb][h][s][0], v1 = at[lb][h][s][1], v2 = at[lb][h][s][2];
        float mx = fmaxf(v0, fmaxf(v1, v2));
        float e0 = expf(v0 - mx), e1 = expf(v1 - mx), e2 = expf(v2 - mx);
        float inv = 1.f / (e0 + e1 + e2);
        at[lb][h][s][0] = e0 * inv; at[lb][h][s][1] = e1 * inv; at[lb][h][s][2] = e2 * inv;
    }
    __syncthreads();

    // o = attn @ v : thread = col j
    {
        int j = tid, h = j >> 6;
#pragma unroll
        for (int lb = 0; lb < 4; lb++)
#pragma unroll
            for (int s = 0; s < 3; s++) {
                float o = at[lb][h][s][0] * qk[lb][0 * 768 + 512 + j]
                        + at[lb][h][s][1] * qk[lb][1 * 768 + 512 + j]
                        + at[lb][h][s][2] * qk[lb][2 * 768 + 512 + j];
                ol[lb * 3 + s][j] = o;
            }
    }
    __syncthreads();

    // out-proj + mean over s. thread: lb = tid>>6 (3 rows), cols tx*4
    {
        const int tx = tid & 63, lb = tid >> 6;
        float a0[4] = {0, 0, 0, 0}, a1[4] = {0, 0, 0, 0}, a2[4] = {0, 0, 0, 0};
        for (int k = 0; k < 256; k++) {
            float4 w = *(const float4*)&Wout[(size_t)k * 256 + tx * 4];
            float wv[4] = {w.x, w.y, w.z, w.w};
            float o0 = ol[lb * 3 + 0][k], o1 = ol[lb * 3 + 1][k], o2 = ol[lb * 3 + 2][k];
#pragma unroll
            for (int c = 0; c < 4; c++) {
                a0[c] = fmaf(o0, wv[c], a0[c]);
                a1[c] = fmaf(o1, wv[c], a1[c]);
                a2[c] = fmaf(o2, wv[c], a2[c]);
            }
        }
        float4 bo = *(const float4*)&bout[tx * 4];
        float bc[4] = {bo.x, bo.y, bo.z, bo.w};
        float f[4];
#pragma unroll
        for (int c = 0; c < 4; c++)
            f[c] = ((a0[c] + bc[c]) + (a1[c] + bc[c]) + (a2[c] + bc[c])) * (1.f / 3.f);
        float4 fv = make_float4(f[0], f[1], f[2], f[3]);
        *(float4*)&fl[lb][tx * 4] = fv;
        *(float4*)&fused[(size_t)(b0 + lb) * NHID + tx * 4] = fv;
    }
    __syncthreads();

    // edge-weight MLP hidden: 4b x 128 = 512 outputs, 2/thread
    {
        int lb = tid >> 6, j = tid & 63;
        float s0 = 0.f, s1 = 0.f;
        for (int k = 0; k < 256; k++) {
            float fv = fl[lb][k];
            s0 = fmaf(fv, W1[(size_t)k * 128 + j], s0);
            s1 = fmaf(fv, W1[(size_t)k * 128 + j + 64], s1);
        }
        h1[lb][j]      = fmaxf(s0 + b1[j], 0.f);
        h1[lb][j + 64] = fmaxf(s1 + b1[j + 64], 0.f);
    }
    __syncthreads();
    if (tid < 4) {
        float s = 0.f;
        for (int j = 0; j < 128; j++) s = fmaf(h1[tid][j], W2[j], s);
        s += b2[0];
        float e = 1.f / (1.f + expf(-s));
        ew[b0 + tid] = fmaxf(e, 1e-8f);
    }
}

// =====================================================================
// K4: logits = F @ F^T, F = fused[8192,256]. 128x128 tile, 8x8 micro.
// =====================================================================
__global__ __launch_bounds__(256) void sim_kernel(
    const float* __restrict__ F, float* __restrict__ C)
{
    __shared__ float As[16][128];
    __shared__ float Bs[16][128];
    const int tid = threadIdx.x;
    const int tx = tid & 15, ty = tid >> 4;
    const int j0 = blockIdx.x * 128;
    const int i0 = blockIdx.y * 128;

    float acc[8][8];
#pragma unroll
    for (int r = 0; r < 8; r++)
#pragma unroll
        for (int c = 0; c < 8; c++) acc[r][c] = 0.f;

    for (int k0 = 0; k0 < 256; k0 += 16) {
        __syncthreads();
#pragma unroll
        for (int i = 0; i < 2; i++) {
            int f4id = i * 256 + tid;
            int row = f4id >> 2, kq = (f4id & 3) << 2;
            float4 va = *(const float4*)&F[(size_t)(i0 + row) * 256 + k0 + kq];
            As[kq + 0][row] = va.x; As[kq + 1][row] = va.y;
            As[kq + 2][row] = va.z; As[kq + 3][row] = va.w;
            float4 vb = *(const float4*)&F[(size_t)(j0 + row) * 256 + k0 + kq];
            Bs[kq + 0][row] = vb.x; Bs[kq + 1][row] = vb.y;
            Bs[kq + 2][row] = vb.z; Bs[kq + 3][row] = vb.w;
        }
        __syncthreads();
#pragma unroll
        for (int kk = 0; kk < 16; kk++) {
            float4 a0 = *(float4*)&As[kk][ty * 8];
            float4 a1 = *(float4*)&As[kk][ty * 8 + 4];
            float4 b0 = *(float4*)&Bs[kk][tx * 4];
            float4 b1 = *(float4*)&Bs[kk][64 + tx * 4];
            float a[8]  = {a0.x, a0.y, a0.z, a0.w, a1.x, a1.y, a1.z, a1.w};
            float bb[8] = {b0.x, b0.y, b0.z, b0.w, b1.x, b1.y, b1.z, b1.w};
#pragma unroll
            for (int r = 0; r < 8; r++)
#pragma unroll
                for (int c = 0; c < 8; c++)
                    acc[r][c] = fmaf(a[r], bb[c], acc[r][c]);
        }
    }

    const int ca = j0 + tx * 4, cb = ca + 64;
#pragma unroll
    for (int r = 0; r < 8; r++) {
        int row = i0 + ty * 8 + r;
        *(float4*)&C[(size_t)row * NB + ca] =
            make_float4(acc[r][0], acc[r][1], acc[r][2], acc[r][3]);
        *(float4*)&C[(size_t)row * NB + cb] =
            make_float4(acc[r][4], acc[r][5], acc[r][6], acc[r][7]);
    }
}

// =====================================================================
// K5: per-row top-8 (stable ties -> lower index) + softmax stats
// block = 256 thr per row; row values stay in registers (32/thread)
// =====================================================================
__device__ __forceinline__ bool better(float a, int ia, float b, int ib) {
    return (a > b) || (a == b && ia < ib);
}

__global__ __launch_bounds__(256) void topk_kernel(
    const float* __restrict__ logits, float* __restrict__ topv, int* __restrict__ topi)
{
    __shared__ float wv[4];
    __shared__ int   wi[4];
    __shared__ float red[4];
    const int row = blockIdx.x;
    const int tid = threadIdx.x;
    const float* L = &logits[(size_t)row * NB];

    float v[32];
#pragma unroll
    for (int q = 0; q < 8; q++) {
        float4 x4 = *(const float4*)&L[(q * 256 + tid) * 4];
        v[q * 4 + 0] = x4.x; v[q * 4 + 1] = x4.y;
        v[q * 4 + 2] = x4.z; v[q * 4 + 3] = x4.w;
    }

    float tv[8]; int ti[8];
#pragma unroll
    for (int s = 0; s < 8; s++) { tv[s] = -3.402823466e38f; ti[s] = 0x7fffffff; }
#pragma unroll
    for (int q = 0; q < 8; q++)
#pragma unroll
        for (int c = 0; c < 4; c++) {
            float nv = v[q * 4 + c];
            int   ni = (q * 256 + tid) * 4 + c;
            if (better(nv, ni, tv[7], ti[7])) {
                tv[7] = nv; ti[7] = ni;
#pragma unroll
                for (int s = 7; s > 0; s--) {
                    if (better(tv[s], ti[s], tv[s - 1], ti[s - 1])) {
                        float tf = tv[s]; tv[s] = tv[s - 1]; tv[s - 1] = tf;
                        int   tt = ti[s]; ti[s] = ti[s - 1]; ti[s - 1] = tt;
                    }
                }
            }
        }

    float rank_v[8]; int rank_i[8];
#pragma unroll
    for (int r = 0; r < 8; r++) {
        float cv = tv[0]; int ci = ti[0];
#pragma unroll
        for (int off = 1; off < 64; off <<= 1) {
            float ov = __shfl_xor(cv, off);
            int   oi = __shfl_xor(ci, off);
            if (better(ov, oi, cv, ci)) { cv = ov; ci = oi; }
        }
        if ((tid & 63) == 0) { wv[tid >> 6] = cv; wi[tid >> 6] = ci; }
        __syncthreads();
        float bv = wv[0]; int bi = wi[0];
#pragma unroll
        for (int w2 = 1; w2 < 4; w2++) {
            if (better(wv[w2], wi[w2], bv, bi)) { bv = wv[w2]; bi = wi[w2]; }
        }
        rank_v[r] = bv; rank_i[r] = bi;
        if (ti[0] == bi) {  // I own the winner: pop front
#pragma unroll
            for (int s = 0; s < 7; s++) { tv[s] = tv[s + 1]; ti[s] = ti[s + 1]; }
            tv[7] = -3.402823466e38f; ti[7] = 0x7fffffff;
        }
        __syncthreads();
    }

    const float mx = rank_v[0];
    float ps = 0.f;
#pragma unroll
    for (int q = 0; q < 32; q++) ps += expf(v[q] - mx);
#pragma unroll
    for (int off = 1; off < 64; off <<= 1) ps += __shfl_xor(ps, off);
    if ((tid & 63) == 0) red[tid >> 6] = ps;
    __syncthreads();
    if (tid == 0) {
        float inv = 1.f / (red[0] + red[1] + red[2] + red[3]);
#pragma unroll
        for (int r = 0; r < 8; r++) {
            topv[(size_t)row * 8 + r] = expf(rank_v[r] - mx) * inv;
            topi[(size_t)row * 8 + r] = rank_i[r];
        }
    }
}

// =====================================================================
// K6: H = eye(B)   (8192 blocks x 256 thr x 8 float4)
// =====================================================================
__global__ __launch_bounds__(256) void hfill_kernel(float* __restrict__ H)
{
    size_t base = (size_t)blockIdx.x * 256 + threadIdx.x;
#pragma unroll
    for (int i = 0; i < 8; i++) {
        size_t id = base + (size_t)i * 2097152;
        size_t p = id * 4;
        int r = (int)(p >> 13);
        int c = (int)(p & 8191);
        float4 o;
        o.x = (c == r)     ? 1.f : 0.f;
        o.y = (c + 1 == r) ? 1.f : 0.f;
        o.z = (c + 2 == r) ? 1.f : 0.f;
        o.w = (c + 3 == r) ? 1.f : 0.f;
        *(float4*)&H[p] = o;
    }
}

// =====================================================================
// K7: scatter H[idx[i][r], i] = val[i][r]
// =====================================================================
__global__ __launch_bounds__(256) void scatter_kernel(
    const float* __restrict__ topv, const int* __restrict__ topi, float* __restrict__ H)
{
    int t = blockIdx.x * 256 + threadIdx.x;  // 65536
    int i = t >> 3;
    H[(size_t)topi[t] * NB + i] = topv[t];
}

// =====================================================================
extern "C" void kernel_launch(void* const* d_in, const int* in_sizes, int n_in,
                              void* d_out, int out_size, void* d_ws, size_t ws_size,
                              hipStream_t stream)
{
    const float* x0  = (const float*)d_in[0];
    const float* Wp0 = (const float*)d_in[1];
    const float* bp0 = (const float*)d_in[2];
    const float* g0  = (const float*)d_in[3];
    const float* be0 = (const float*)d_in[4];
    const float* x1  = (const float*)d_in[5];
    const float* Wp1 = (const float*)d_in[6];
    const float* bp1 = (const float*)d_in[7];
    const float* g1  = (const float*)d_in[8];
    const float* be1 = (const float*)d_in[9];
    const float* x2  = (const float*)d_in[10];
    const float* Wp2 = (const float*)d_in[11];
    const float* bp2 = (const float*)d_in[12];
    const float* g2  = (const float*)d_in[13];
    const float* be2 = (const float*)d_in[14];
    const float* Win = (const float*)d_in[15];
    const float* bin = (const float*)d_in[16];
    const float* Wout= (const float*)d_in[17];
    const float* bout= (const float*)d_in[18];
    const float* W1  = (const float*)d_in[19];
    const float* b1  = (const float*)d_in[20];
    const float* W2  = (const float*)d_in[21];
    const float* b2  = (const float*)d_in[22];

    float* out = (float*)d_out;
    float* ws  = (float*)d_ws;

    // scratch inside d_out (dead before the logits overwrite them):
    float* qkv = out;                    // [0,            18874368)   24576x768
    float* seq = out + 18874368;         // [18874368,     25165824)   24576x256
    // persistent scratch in d_ws (~9 MB):
    float* fused = ws;                   // 8192x256
    float* topv  = ws + 2097152;         // 8192x8
    int*   topi  = (int*)(ws + 2162688); // 8192x8
    float* ew    = out + (size_t)NB * NB;

    proj_ln_kernel<<<dim3(256, 3), 256, 0, stream>>>(
        x0, Wp0, bp0, g0, be0, x1, Wp1, bp1, g1, be1, x2, Wp2, bp2, g2, be2, seq);
    qkv_kernel<<<dim3(6, 192), 256, 0, stream>>>(seq, Win, bin, qkv);
    attn_kernel<<<2048, 256, 0, stream>>>(qkv, Wout, bout, W1, b1, W2, b2, fused, ew);
    sim_kernel<<<dim3(64, 64), 256, 0, stream>>>(fused, out);
    topk_kernel<<<8192, 256, 0, stream>>>(out, topv, topi);
    hfill_kernel<<<8192, 256, 0, stream>>>(out);
    scatter_kernel<<<256, 256, 0, stream>>>(topv, topi, out);
}

// Round 2
// 1162.765 us; speedup vs baseline: 1.2098x; 1.2098x over previous
//
#include <hip/hip_runtime.h>
#include <hip/hip_bf16.h>
#include <math.h>

#define NB 8192
#define NHID 256

typedef __attribute__((ext_vector_type(8))) short short8;
typedef __attribute__((ext_vector_type(4))) float f32x4;
typedef unsigned short u16;

typedef __attribute__((address_space(3))) unsigned char* as3_u8;
typedef const __attribute__((address_space(1))) unsigned char* as1_cu8;
#define GLOAD_LDS16(g, l) \
    __builtin_amdgcn_global_load_lds((as1_cu8)(g), (as3_u8)(l), 16, 0, 0)

// =====================================================================
// K1: per-modality Linear -> ReLU -> LayerNorm, writes seq[(b*3+m)][256]
// =====================================================================
__global__ __launch_bounds__(256) void proj_ln_kernel(
    const float* __restrict__ x0, const float* __restrict__ Wp0, const float* __restrict__ bp0,
    const float* __restrict__ g0, const float* __restrict__ be0,
    const float* __restrict__ x1, const float* __restrict__ Wp1, const float* __restrict__ bp1,
    const float* __restrict__ g1, const float* __restrict__ be1,
    const float* __restrict__ x2, const float* __restrict__ Wp2, const float* __restrict__ bp2,
    const float* __restrict__ g2, const float* __restrict__ be2,
    float* __restrict__ seq)
{
    const int m = blockIdx.y;
    const float* x; const float* Wp; const float* bp; const float* g; const float* be; int d;
    if (m == 0)      { x = x0; Wp = Wp0; bp = bp0; g = g0; be = be0; d = 512; }
    else if (m == 1) { x = x1; Wp = Wp1; bp = bp1; g = g1; be = be1; d = 768; }
    else             { x = x2; Wp = Wp2; bp = bp2; g = g2; be = be2; d = 1024; }

    __shared__ float As[16][32];
    __shared__ float Bs[16][256];

    const int tid = threadIdx.x;
    const int tx = tid & 63;
    const int ty = tid >> 6;
    const int r0 = blockIdx.x * 32;

    float acc[8][4];
#pragma unroll
    for (int r = 0; r < 8; r++)
#pragma unroll
        for (int c = 0; c < 4; c++) acc[r][c] = 0.f;

    for (int k0 = 0; k0 < d; k0 += 16) {
        __syncthreads();
        {
            int eid = tid * 2;
            int row = eid >> 4, kk = eid & 15;
            float2 v = *(const float2*)&x[(size_t)(r0 + row) * d + k0 + kk];
            As[kk][row]     = v.x;
            As[kk + 1][row] = v.y;
        }
#pragma unroll
        for (int i = 0; i < 4; i++) {
            int f4id = i * 256 + tid;
            int kk = f4id >> 6, c4 = f4id & 63;
            *(float4*)&Bs[kk][c4 * 4] =
                *(const float4*)&Wp[(size_t)(k0 + kk) * NHID + c4 * 4];
        }
        __syncthreads();
#pragma unroll
        for (int kk = 0; kk < 16; kk++) {
            float4 a0 = *(float4*)&As[kk][ty * 8];
            float4 a1 = *(float4*)&As[kk][ty * 8 + 4];
            float4 b  = *(float4*)&Bs[kk][tx * 4];
            float ar[8] = {a0.x, a0.y, a0.z, a0.w, a1.x, a1.y, a1.z, a1.w};
            float bc[4] = {b.x, b.y, b.z, b.w};
#pragma unroll
            for (int r = 0; r < 8; r++)
#pragma unroll
                for (int c = 0; c < 4; c++)
                    acc[r][c] = fmaf(ar[r], bc[c], acc[r][c]);
        }
    }

    const int colb = tx * 4;
    float4 bpv = *(const float4*)&bp[colb];
    float4 gv  = *(const float4*)&g[colb];
    float4 bev = *(const float4*)&be[colb];
    float bpc[4] = {bpv.x, bpv.y, bpv.z, bpv.w};
    float gc[4]  = {gv.x, gv.y, gv.z, gv.w};
    float bec[4] = {bev.x, bev.y, bev.z, bev.w};

#pragma unroll
    for (int r = 0; r < 8; r++) {
        float y[4];
#pragma unroll
        for (int c = 0; c < 4; c++) y[c] = fmaxf(acc[r][c] + bpc[c], 0.f);
        float s  = y[0] + y[1] + y[2] + y[3];
        float s2 = y[0]*y[0] + y[1]*y[1] + y[2]*y[2] + y[3]*y[3];
#pragma unroll
        for (int off = 1; off < 64; off <<= 1) {
            s  += __shfl_xor(s, off);
            s2 += __shfl_xor(s2, off);
        }
        float meanv = s * (1.f / 256.f);
        float varv  = s2 * (1.f / 256.f) - meanv * meanv;
        float inv   = 1.f / sqrtf(varv + 1e-5f);
        float4 o;
        o.x = (y[0] - meanv) * inv * gc[0] + bec[0];
        o.y = (y[1] - meanv) * inv * gc[1] + bec[1];
        o.z = (y[2] - meanv) * inv * gc[2] + bec[2];
        o.w = (y[3] - meanv) * inv * gc[3] + bec[3];
        *(float4*)&seq[((size_t)(r0 + ty * 8 + r) * 3 + m) * NHID + colb] = o;
    }
}

// =====================================================================
// K2: qkv = seq[24576,256] @ Win[256,768] + bin
// =====================================================================
__global__ __launch_bounds__(256) void qkv_kernel(
    const float* __restrict__ seq, const float* __restrict__ Win,
    const float* __restrict__ bin, float* __restrict__ qkv)
{
    __shared__ float As[16][128];
    __shared__ float Bs[16][128];
    const int tid = threadIdx.x;
    const int tx = tid & 15, ty = tid >> 4;
    const int c0 = blockIdx.x * 128;
    const int r0 = blockIdx.y * 128;

    float acc[8][8];
#pragma unroll
    for (int r = 0; r < 8; r++)
#pragma unroll
        for (int c = 0; c < 8; c++) acc[r][c] = 0.f;

    for (int k0 = 0; k0 < 256; k0 += 16) {
        __syncthreads();
#pragma unroll
        for (int i = 0; i < 2; i++) {
            int f4id = i * 256 + tid;
            int row = f4id >> 2, kq = (f4id & 3) << 2;
            float4 v = *(const float4*)&seq[(size_t)(r0 + row) * 256 + k0 + kq];
            As[kq + 0][row] = v.x; As[kq + 1][row] = v.y;
            As[kq + 2][row] = v.z; As[kq + 3][row] = v.w;
        }
#pragma unroll
        for (int i = 0; i < 2; i++) {
            int f4id = i * 256 + tid;
            int kk = f4id >> 5, c4 = f4id & 31;
            *(float4*)&Bs[kk][c4 * 4] =
                *(const float4*)&Win[(size_t)(k0 + kk) * 768 + c0 + c4 * 4];
        }
        __syncthreads();
#pragma unroll
        for (int kk = 0; kk < 16; kk++) {
            float4 a0 = *(float4*)&As[kk][ty * 8];
            float4 a1 = *(float4*)&As[kk][ty * 8 + 4];
            float4 b0 = *(float4*)&Bs[kk][tx * 4];
            float4 b1 = *(float4*)&Bs[kk][64 + tx * 4];
            float a[8]  = {a0.x, a0.y, a0.z, a0.w, a1.x, a1.y, a1.z, a1.w};
            float bb[8] = {b0.x, b0.y, b0.z, b0.w, b1.x, b1.y, b1.z, b1.w};
#pragma unroll
            for (int r = 0; r < 8; r++)
#pragma unroll
                for (int c = 0; c < 8; c++)
                    acc[r][c] = fmaf(a[r], bb[c], acc[r][c]);
        }
    }

    const int ca = c0 + tx * 4, cb = ca + 64;
    float4 ba  = *(const float4*)&bin[ca];
    float4 bb4 = *(const float4*)&bin[cb];
#pragma unroll
    for (int r = 0; r < 8; r++) {
        int row = r0 + ty * 8 + r;
        float4 oa = make_float4(acc[r][0] + ba.x,  acc[r][1] + ba.y,
                                acc[r][2] + ba.z,  acc[r][3] + ba.w);
        float4 ob = make_float4(acc[r][4] + bb4.x, acc[r][5] + bb4.y,
                                acc[r][6] + bb4.z, acc[r][7] + bb4.w);
        *(float4*)&qkv[(size_t)row * 768 + ca] = oa;
        *(float4*)&qkv[(size_t)row * 768 + cb] = ob;
    }
}

// =====================================================================
// K3: attention + out-proj + mean + edge MLP; writes Fh/Fl (bf16 split)
// =====================================================================
__global__ __launch_bounds__(256) void attn_kernel(
    const float* __restrict__ qkv, const float* __restrict__ Wout,
    const float* __restrict__ bout, const float* __restrict__ W1,
    const float* __restrict__ b1, const float* __restrict__ W2,
    const float* __restrict__ b2, u16* __restrict__ Fh, u16* __restrict__ Fl,
    float* __restrict__ ew)
{
    __shared__ float qk[4][2304];
    __shared__ float at[4][4][3][3];
    __shared__ float ol[12][256];
    __shared__ float fl[4][256];
    __shared__ float h1[4][128];

    const int tid = threadIdx.x;
    const int b0 = blockIdx.x * 4;

#pragma unroll
    for (int i = 0; i < 9; i++) {
        int f4 = i * 256 + tid;
        int lb = f4 / 576, rem = f4 - lb * 576;
        *(float4*)&qk[lb][rem * 4] =
            *(const float4*)&qkv[(size_t)(b0 + lb) * 2304 + rem * 4];
    }
    __syncthreads();

    if (tid < 144) {
        int lb = tid / 36, r = tid % 36;
        int h = r / 9, s = (r / 3) % 3, t = r % 3;
        const float* qp = &qk[lb][s * 768 + h * 64];
        const float* kp = &qk[lb][t * 768 + 256 + h * 64];
        float sum = 0.f;
#pragma unroll
        for (int dd = 0; dd < 64; dd++) sum = fmaf(qp[dd], kp[dd], sum);
        at[lb][h][s][t] = sum * 0.125f;
    }
    __syncthreads();

    if (tid < 48) {
        int lb = tid / 12, h = (tid / 3) % 4, s = tid % 3;
        float v0 = at[lb][h][s][0], v1 = at[lb][h][s][1], v2 = at[lb][h][s][2];
        float mx = fmaxf(v0, fmaxf(v1, v2));
        float e0 = expf(v0 - mx), e1 = expf(v1 - mx), e2 = expf(v2 - mx);
        float inv = 1.f / (e0 + e1 + e2);
        at[lb][h][s][0] = e0 * inv; at[lb][h][s][1] = e1 * inv; at[lb][h][s][2] = e2 * inv;
    }
    __syncthreads();

    {
        int j = tid, h = j >> 6;
#pragma unroll
        for (int lb = 0; lb < 4; lb++)
#pragma unroll
            for (int s = 0; s < 3; s++) {
                float o = at[lb][h][s][0] * qk[lb][0 * 768 + 512 + j]
                        + at[lb][h][s][1] * qk[lb][1 * 768 + 512 + j]
                        + at[lb][h][s][2] * qk[lb][2 * 768 + 512 + j];
                ol[lb * 3 + s][j] = o;
            }
    }
    __syncthreads();

    {
        const int txx = tid & 63, lbb = tid >> 6;
        float a0[4] = {0, 0, 0, 0}, a1[4] = {0, 0, 0, 0}, a2[4] = {0, 0, 0, 0};
        for (int k = 0; k < 256; k++) {
            float4 w = *(const float4*)&Wout[(size_t)k * 256 + txx * 4];
            float wv[4] = {w.x, w.y, w.z, w.w};
            float o0 = ol[lbb * 3 + 0][k], o1 = ol[lbb * 3 + 1][k], o2 = ol[lbb * 3 + 2][k];
#pragma unroll
            for (int c = 0; c < 4; c++) {
                a0[c] = fmaf(o0, wv[c], a0[c]);
                a1[c] = fmaf(o1, wv[c], a1[c]);
                a2[c] = fmaf(o2, wv[c], a2[c]);
            }
        }
        float4 bo = *(const float4*)&bout[txx * 4];
        float bc[4] = {bo.x, bo.y, bo.z, bo.w};
        float f[4];
        u16 hq[4], lq[4];
#pragma unroll
        for (int c = 0; c < 4; c++) {
            f[c] = ((a0[c] + bc[c]) + (a1[c] + bc[c]) + (a2[c] + bc[c])) * (1.f / 3.f);
            __hip_bfloat16 hb = __float2bfloat16(f[c]);
            float fh = __bfloat162float(hb);
            __hip_bfloat16 lb2 = __float2bfloat16(f[c] - fh);
            hq[c] = *(u16*)&hb;
            lq[c] = *(u16*)&lb2;
        }
        *(float4*)&fl[lbb][txx * 4] = make_float4(f[0], f[1], f[2], f[3]);
        uint2 hp, lp;
        hp.x = (unsigned)hq[0] | ((unsigned)hq[1] << 16);
        hp.y = (unsigned)hq[2] | ((unsigned)hq[3] << 16);
        lp.x = (unsigned)lq[0] | ((unsigned)lq[1] << 16);
        lp.y = (unsigned)lq[2] | ((unsigned)lq[3] << 16);
        *(uint2*)&Fh[(size_t)(b0 + lbb) * NHID + txx * 4] = hp;
        *(uint2*)&Fl[(size_t)(b0 + lbb) * NHID + txx * 4] = lp;
    }
    __syncthreads();

    {
        int lb = tid >> 6, j = tid & 63;
        float s0 = 0.f, s1 = 0.f;
        for (int k = 0; k < 256; k++) {
            float fv = fl[lb][k];
            s0 = fmaf(fv, W1[(size_t)k * 128 + j], s0);
            s1 = fmaf(fv, W1[(size_t)k * 128 + j + 64], s1);
        }
        h1[lb][j]      = fmaxf(s0 + b1[j], 0.f);
        h1[lb][j + 64] = fmaxf(s1 + b1[j + 64], 0.f);
    }
    __syncthreads();
    if (tid < 4) {
        float s = 0.f;
        for (int j = 0; j < 128; j++) s = fmaf(h1[tid][j], W2[j], s);
        s += b2[0];
        float e = 1.f / (1.f + expf(-s));
        ew[b0 + tid] = fmaxf(e, 1e-8f);
    }
}

// =====================================================================
// K4: logits = F F^T via 3-term bf16 split MFMA GEMM, K' = 768
//   segments: seg0 A=Fh B=Fh, seg1 A=Fl B=Fh, seg2 A=Fh B=Fl
// 128x128 tile, BK=64, 4 waves (2x2), wave tile 64x64 (4x4 frags 16x16x32)
// LDS linear [128][64] bf16 per operand; XOR swizzle slot^=(row&7) applied
// to the GLOBAL source (global_load_lds writes linearly) and to ds_read.
// =====================================================================
__global__ __launch_bounds__(256) void sim_mfma_kernel(
    const u16* __restrict__ Fh, const u16* __restrict__ Fl, float* __restrict__ C)
{
    __shared__ __align__(16) unsigned char smem[32768];  // A:0..16K, B:16K..32K

    const int tid  = threadIdx.x;
    const int lane = tid & 63;
    const int w    = tid >> 6;        // wave 0..3
    const int wr   = w >> 1;          // wave row (i-dim)
    const int wc   = w & 1;           // wave col (j-dim)
    const int lr   = lane & 15;       // frag row
    const int lg   = lane >> 4;       // k-group 0..3

    // XCD-bijective swizzle (4096 % 8 == 0)
    const int orig = blockIdx.x;
    const int wg   = ((orig & 7) << 9) | (orig >> 3);
    const int i0   = (wg >> 6) << 7;
    const int j0   = (wg & 63) << 7;

    // staging: per wave 4 insts/operand, each inst = 8 rows x 64 bf16 (1KB)
    const int srow  = lane >> 3;                    // 0..7 row within inst
    const int sslot = (lane & 7) ^ srow;            // pre-swizzled k-slot
    const int acol  = sslot * 8;                    // bf16 col offset

    f32x4 acc[4][4];
#pragma unroll
    for (int a = 0; a < 4; a++)
#pragma unroll
        for (int b = 0; b < 4; b++) acc[a][b] = (f32x4)0.f;

    for (int kt = 0; kt < 12; kt++) {
        const int seg  = kt >> 2;
        const int kloc = (kt & 3) << 6;
        const u16* Ag = (seg == 1) ? Fl : Fh;
        const u16* Bg = (seg == 2) ? Fl : Fh;

        __syncthreads();
#pragma unroll
        for (int i = 0; i < 4; i++) {
            const int rbase = w * 32 + i * 8;
            GLOAD_LDS16(&Ag[(size_t)(i0 + rbase + srow) * NHID + kloc + acol],
                        smem + rbase * 128);
            GLOAD_LDS16(&Bg[(size_t)(j0 + rbase + srow) * NHID + kloc + acol],
                        smem + 16384 + rbase * 128);
        }
        __syncthreads();

#pragma unroll
        for (int ks = 0; ks < 2; ks++) {
            short8 av[4], bv[4];
            const int slotx = ((ks * 4 + lg) ^ (lr & 7)) * 16;
#pragma unroll
            for (int f = 0; f < 4; f++) {
                av[f] = *(const short8*)(smem + (wr * 64 + f * 16 + lr) * 128 + slotx);
                bv[f] = *(const short8*)(smem + 16384 + (wc * 64 + f * 16 + lr) * 128 + slotx);
            }
#pragma unroll
            for (int fj = 0; fj < 4; fj++)
#pragma unroll
                for (int fi = 0; fi < 4; fi++)
                    acc[fj][fi] = __builtin_amdgcn_mfma_f32_16x16x32_bf16(
                        bv[fj], av[fi], acc[fj][fi], 0, 0, 0);
        }
    }

    // lane's 4 regs of acc[fj][fi] = 4 consecutive COLUMNS at one row
#pragma unroll
    for (int fj = 0; fj < 4; fj++)
#pragma unroll
        for (int fi = 0; fi < 4; fi++) {
            const int r = i0 + wr * 64 + fi * 16 + lr;
            const int c = j0 + wc * 64 + fj * 16 + lg * 4;
            *(f32x4*)&C[(size_t)r * NB + c] = acc[fj][fi];
        }
}

// =====================================================================
// K5: per-row top-8 + softmax stats; then overwrite row with eye row
// =====================================================================
__device__ __forceinline__ bool better(float a, int ia, float b, int ib) {
    return (a > b) || (a == b && ia < ib);
}

__global__ __launch_bounds__(256) void topk_kernel(
    float* __restrict__ logits, float* __restrict__ topv, int* __restrict__ topi)
{
    __shared__ float wv[4];
    __shared__ int   wi[4];
    __shared__ float red[4];
    const int row = blockIdx.x;
    const int tid = threadIdx.x;
    float* L = &logits[(size_t)row * NB];

    float v[32];
#pragma unroll
    for (int q = 0; q < 8; q++) {
        float4 x4 = *(const float4*)&L[(q * 256 + tid) * 4];
        v[q * 4 + 0] = x4.x; v[q * 4 + 1] = x4.y;
        v[q * 4 + 2] = x4.z; v[q * 4 + 3] = x4.w;
    }

    float tv[8]; int ti[8];
#pragma unroll
    for (int s = 0; s < 8; s++) { tv[s] = -3.402823466e38f; ti[s] = 0x7fffffff; }
#pragma unroll
    for (int q = 0; q < 8; q++)
#pragma unroll
        for (int c = 0; c < 4; c++) {
            float nv = v[q * 4 + c];
            int   ni = (q * 256 + tid) * 4 + c;
            if (better(nv, ni, tv[7], ti[7])) {
                tv[7] = nv; ti[7] = ni;
#pragma unroll
                for (int s = 7; s > 0; s--) {
                    if (better(tv[s], ti[s], tv[s - 1], ti[s - 1])) {
                        float tf = tv[s]; tv[s] = tv[s - 1]; tv[s - 1] = tf;
                        int   tt = ti[s]; ti[s] = ti[s - 1]; ti[s - 1] = tt;
                    }
                }
            }
        }

    float rank_v[8]; int rank_i[8];
#pragma unroll
    for (int r = 0; r < 8; r++) {
        float cv = tv[0]; int ci = ti[0];
#pragma unroll
        for (int off = 1; off < 64; off <<= 1) {
            float ov = __shfl_xor(cv, off);
            int   oi = __shfl_xor(ci, off);
            if (better(ov, oi, cv, ci)) { cv = ov; ci = oi; }
        }
        if ((tid & 63) == 0) { wv[tid >> 6] = cv; wi[tid >> 6] = ci; }
        __syncthreads();
        float bv = wv[0]; int bi = wi[0];
#pragma unroll
        for (int w2 = 1; w2 < 4; w2++) {
            if (better(wv[w2], wi[w2], bv, bi)) { bv = wv[w2]; bi = wi[w2]; }
        }
        rank_v[r] = bv; rank_i[r] = bi;
        if (ti[0] == bi) {
#pragma unroll
            for (int s = 0; s < 7; s++) { tv[s] = tv[s + 1]; ti[s] = ti[s + 1]; }
            tv[7] = -3.402823466e38f; ti[7] = 0x7fffffff;
        }
        __syncthreads();
    }

    const float mx = rank_v[0];
    float ps = 0.f;
#pragma unroll
    for (int q = 0; q < 32; q++) ps += expf(v[q] - mx);
#pragma unroll
    for (int off = 1; off < 64; off <<= 1) ps += __shfl_xor(ps, off);
    if ((tid & 63) == 0) red[tid >> 6] = ps;
    __syncthreads();
    if (tid == 0) {
        float inv = 1.f / (red[0] + red[1] + red[2] + red[3]);
#pragma unroll
        for (int r = 0; r < 8; r++) {
            topv[(size_t)row * 8 + r] = expf(rank_v[r] - mx) * inv;
            topi[(size_t)row * 8 + r] = rank_i[r];
        }
    }

    // overwrite this row with the identity row (fused former hfill kernel)
    __syncthreads();
#pragma unroll
    for (int q = 0; q < 8; q++) {
        int c4 = (q * 256 + tid) * 4;
        float4 o;
        o.x = (c4 == row)     ? 1.f : 0.f;
        o.y = (c4 + 1 == row) ? 1.f : 0.f;
        o.z = (c4 + 2 == row) ? 1.f : 0.f;
        o.w = (c4 + 3 == row) ? 1.f : 0.f;
        *(float4*)&L[c4] = o;
    }
}

// =====================================================================
// K7: scatter H[idx[i][r], i] = val[i][r]
// =====================================================================
__global__ __launch_bounds__(256) void scatter_kernel(
    const float* __restrict__ topv, const int* __restrict__ topi, float* __restrict__ H)
{
    int t = blockIdx.x * 256 + threadIdx.x;
    int i = t >> 3;
    H[(size_t)topi[t] * NB + i] = topv[t];
}

// =====================================================================
extern "C" void kernel_launch(void* const* d_in, const int* in_sizes, int n_in,
                              void* d_out, int out_size, void* d_ws, size_t ws_size,
                              hipStream_t stream)
{
    const float* x0  = (const float*)d_in[0];
    const float* Wp0 = (const float*)d_in[1];
    const float* bp0 = (const float*)d_in[2];
    const float* g0  = (const float*)d_in[3];
    const float* be0 = (const float*)d_in[4];
    const float* x1  = (const float*)d_in[5];
    const float* Wp1 = (const float*)d_in[6];
    const float* bp1 = (const float*)d_in[7];
    const float* g1  = (const float*)d_in[8];
    const float* be1 = (const float*)d_in[9];
    const float* x2  = (const float*)d_in[10];
    const float* Wp2 = (const float*)d_in[11];
    const float* bp2 = (const float*)d_in[12];
    const float* g2  = (const float*)d_in[13];
    const float* be2 = (const float*)d_in[14];
    const float* Win = (const float*)d_in[15];
    const float* bin = (const float*)d_in[16];
    const float* Wout= (const float*)d_in[17];
    const float* bout= (const float*)d_in[18];
    const float* W1  = (const float*)d_in[19];
    const float* b1  = (const float*)d_in[20];
    const float* W2  = (const float*)d_in[21];
    const float* b2  = (const float*)d_in[22];

    float* out = (float*)d_out;

    // scratch inside d_out (dead before the logits overwrite them):
    float* qkv = out;                    // 24576x768
    float* seq = out + 18874368;         // 24576x256
    // persistent scratch in d_ws (~8.5 MB):
    u16*   Fh   = (u16*)d_ws;                              // 8192x256 bf16 (4 MB)
    u16*   Fl   = (u16*)((char*)d_ws + (4u << 20));        // 8192x256 bf16 (4 MB)
    float* topv = (float*)((char*)d_ws + (8u << 20));      // 8192x8 (256 KB)
    int*   topi = (int*)((char*)d_ws + (8u << 20) + 262144);
    float* ew   = out + (size_t)NB * NB;

    proj_ln_kernel<<<dim3(256, 3), 256, 0, stream>>>(
        x0, Wp0, bp0, g0, be0, x1, Wp1, bp1, g1, be1, x2, Wp2, bp2, g2, be2, seq);
    qkv_kernel<<<dim3(6, 192), 256, 0, stream>>>(seq, Win, bin, qkv);
    attn_kernel<<<2048, 256, 0, stream>>>(qkv, Wout, bout, W1, b1, W2, b2, Fh, Fl, ew);
    sim_mfma_kernel<<<4096, 256, 0, stream>>>(Fh, Fl, out);
    topk_kernel<<<8192, 256, 0, stream>>>(out, topv, topi);
    scatter_kernel<<<256, 256, 0, stream>>>(topv, topi, out);
}

// Round 3
// 970.144 us; speedup vs baseline: 1.4500x; 1.1985x over previous
//
#include <hip/hip_runtime.h>
#include <hip/hip_bf16.h>
#include <math.h>

#define NB 8192
#define NHID 256

typedef __attribute__((ext_vector_type(8))) short short8;
typedef __attribute__((ext_vector_type(4))) float f32x4;
typedef unsigned short u16;

typedef __attribute__((address_space(3))) unsigned char* as3_u8;
typedef const __attribute__((address_space(1))) unsigned char* as1_cu8;
#define GLOAD_LDS16(g, l) \
    __builtin_amdgcn_global_load_lds((as1_cu8)(g), (as3_u8)(l), 16, 0, 0)

// =====================================================================
// K1: per-modality Linear -> ReLU -> LayerNorm, writes seq[(b*3+m)][256]
// =====================================================================
__global__ __launch_bounds__(256) void proj_ln_kernel(
    const float* __restrict__ x0, const float* __restrict__ Wp0, const float* __restrict__ bp0,
    const float* __restrict__ g0, const float* __restrict__ be0,
    const float* __restrict__ x1, const float* __restrict__ Wp1, const float* __restrict__ bp1,
    const float* __restrict__ g1, const float* __restrict__ be1,
    const float* __restrict__ x2, const float* __restrict__ Wp2, const float* __restrict__ bp2,
    const float* __restrict__ g2, const float* __restrict__ be2,
    float* __restrict__ seq)
{
    const int m = blockIdx.y;
    const float* x; const float* Wp; const float* bp; const float* g; const float* be; int d;
    if (m == 0)      { x = x0; Wp = Wp0; bp = bp0; g = g0; be = be0; d = 512; }
    else if (m == 1) { x = x1; Wp = Wp1; bp = bp1; g = g1; be = be1; d = 768; }
    else             { x = x2; Wp = Wp2; bp = bp2; g = g2; be = be2; d = 1024; }

    __shared__ float As[16][32];
    __shared__ float Bs[16][256];

    const int tid = threadIdx.x;
    const int tx = tid & 63;
    const int ty = tid >> 6;
    const int r0 = blockIdx.x * 32;

    float acc[8][4];
#pragma unroll
    for (int r = 0; r < 8; r++)
#pragma unroll
        for (int c = 0; c < 4; c++) acc[r][c] = 0.f;

    for (int k0 = 0; k0 < d; k0 += 16) {
        __syncthreads();
        {
            int eid = tid * 2;
            int row = eid >> 4, kk = eid & 15;
            float2 v = *(const float2*)&x[(size_t)(r0 + row) * d + k0 + kk];
            As[kk][row]     = v.x;
            As[kk + 1][row] = v.y;
        }
#pragma unroll
        for (int i = 0; i < 4; i++) {
            int f4id = i * 256 + tid;
            int kk = f4id >> 6, c4 = f4id & 63;
            *(float4*)&Bs[kk][c4 * 4] =
                *(const float4*)&Wp[(size_t)(k0 + kk) * NHID + c4 * 4];
        }
        __syncthreads();
#pragma unroll
        for (int kk = 0; kk < 16; kk++) {
            float4 a0 = *(float4*)&As[kk][ty * 8];
            float4 a1 = *(float4*)&As[kk][ty * 8 + 4];
            float4 b  = *(float4*)&Bs[kk][tx * 4];
            float ar[8] = {a0.x, a0.y, a0.z, a0.w, a1.x, a1.y, a1.z, a1.w};
            float bc[4] = {b.x, b.y, b.z, b.w};
#pragma unroll
            for (int r = 0; r < 8; r++)
#pragma unroll
                for (int c = 0; c < 4; c++)
                    acc[r][c] = fmaf(ar[r], bc[c], acc[r][c]);
        }
    }

    const int colb = tx * 4;
    float4 bpv = *(const float4*)&bp[colb];
    float4 gv  = *(const float4*)&g[colb];
    float4 bev = *(const float4*)&be[colb];
    float bpc[4] = {bpv.x, bpv.y, bpv.z, bpv.w};
    float gc[4]  = {gv.x, gv.y, gv.z, gv.w};
    float bec[4] = {bev.x, bev.y, bev.z, bev.w};

#pragma unroll
    for (int r = 0; r < 8; r++) {
        float y[4];
#pragma unroll
        for (int c = 0; c < 4; c++) y[c] = fmaxf(acc[r][c] + bpc[c], 0.f);
        float s  = y[0] + y[1] + y[2] + y[3];
        float s2 = y[0]*y[0] + y[1]*y[1] + y[2]*y[2] + y[3]*y[3];
#pragma unroll
        for (int off = 1; off < 64; off <<= 1) {
            s  += __shfl_xor(s, off);
            s2 += __shfl_xor(s2, off);
        }
        float meanv = s * (1.f / 256.f);
        float varv  = s2 * (1.f / 256.f) - meanv * meanv;
        float inv   = 1.f / sqrtf(varv + 1e-5f);
        float4 o;
        o.x = (y[0] - meanv) * inv * gc[0] + bec[0];
        o.y = (y[1] - meanv) * inv * gc[1] + bec[1];
        o.z = (y[2] - meanv) * inv * gc[2] + bec[2];
        o.w = (y[3] - meanv) * inv * gc[3] + bec[3];
        *(float4*)&seq[((size_t)(r0 + ty * 8 + r) * 3 + m) * NHID + colb] = o;
    }
}

// =====================================================================
// K2: qkv = seq[24576,256] @ Win[256,768] + bin
// =====================================================================
__global__ __launch_bounds__(256) void qkv_kernel(
    const float* __restrict__ seq, const float* __restrict__ Win,
    const float* __restrict__ bin, float* __restrict__ qkv)
{
    __shared__ float As[16][128];
    __shared__ float Bs[16][128];
    const int tid = threadIdx.x;
    const int tx = tid & 15, ty = tid >> 4;
    const int c0 = blockIdx.x * 128;
    const int r0 = blockIdx.y * 128;

    float acc[8][8];
#pragma unroll
    for (int r = 0; r < 8; r++)
#pragma unroll
        for (int c = 0; c < 8; c++) acc[r][c] = 0.f;

    for (int k0 = 0; k0 < 256; k0 += 16) {
        __syncthreads();
#pragma unroll
        for (int i = 0; i < 2; i++) {
            int f4id = i * 256 + tid;
            int row = f4id >> 2, kq = (f4id & 3) << 2;
            float4 v = *(const float4*)&seq[(size_t)(r0 + row) * 256 + k0 + kq];
            As[kq + 0][row] = v.x; As[kq + 1][row] = v.y;
            As[kq + 2][row] = v.z; As[kq + 3][row] = v.w;
        }
#pragma unroll
        for (int i = 0; i < 2; i++) {
            int f4id = i * 256 + tid;
            int kk = f4id >> 5, c4 = f4id & 31;
            *(float4*)&Bs[kk][c4 * 4] =
                *(const float4*)&Win[(size_t)(k0 + kk) * 768 + c0 + c4 * 4];
        }
        __syncthreads();
#pragma unroll
        for (int kk = 0; kk < 16; kk++) {
            float4 a0 = *(float4*)&As[kk][ty * 8];
            float4 a1 = *(float4*)&As[kk][ty * 8 + 4];
            float4 b0 = *(float4*)&Bs[kk][tx * 4];
            float4 b1 = *(float4*)&Bs[kk][64 + tx * 4];
            float a[8]  = {a0.x, a0.y, a0.z, a0.w, a1.x, a1.y, a1.z, a1.w};
            float bb[8] = {b0.x, b0.y, b0.z, b0.w, b1.x, b1.y, b1.z, b1.w};
#pragma unroll
            for (int r = 0; r < 8; r++)
#pragma unroll
                for (int c = 0; c < 8; c++)
                    acc[r][c] = fmaf(a[r], bb[c], acc[r][c]);
        }
    }

    const int ca = c0 + tx * 4, cb = ca + 64;
    float4 ba  = *(const float4*)&bin[ca];
    float4 bb4 = *(const float4*)&bin[cb];
#pragma unroll
    for (int r = 0; r < 8; r++) {
        int row = r0 + ty * 8 + r;
        float4 oa = make_float4(acc[r][0] + ba.x,  acc[r][1] + ba.y,
                                acc[r][2] + ba.z,  acc[r][3] + ba.w);
        float4 ob = make_float4(acc[r][4] + bb4.x, acc[r][5] + bb4.y,
                                acc[r][6] + bb4.z, acc[r][7] + bb4.w);
        *(float4*)&qkv[(size_t)row * 768 + ca] = oa;
        *(float4*)&qkv[(size_t)row * 768 + cb] = ob;
    }
}

// =====================================================================
// K3: attention + out-proj + mean + edge MLP; writes Fh/Fl (bf16 split)
// =====================================================================
__global__ __launch_bounds__(256) void attn_kernel(
    const float* __restrict__ qkv, const float* __restrict__ Wout,
    const float* __restrict__ bout, const float* __restrict__ W1,
    const float* __restrict__ b1, const float* __restrict__ W2,
    const float* __restrict__ b2, u16* __restrict__ Fh, u16* __restrict__ Fl,
    float* __restrict__ ew)
{
    __shared__ float qk[4][2304];
    __shared__ float at[4][4][3][3];
    __shared__ float ol[12][256];
    __shared__ float fl[4][256];
    __shared__ float h1[4][128];

    const int tid = threadIdx.x;
    const int b0 = blockIdx.x * 4;

#pragma unroll
    for (int i = 0; i < 9; i++) {
        int f4 = i * 256 + tid;
        int lb = f4 / 576, rem = f4 - lb * 576;
        *(float4*)&qk[lb][rem * 4] =
            *(const float4*)&qkv[(size_t)(b0 + lb) * 2304 + rem * 4];
    }
    __syncthreads();

    if (tid < 144) {
        int lb = tid / 36, r = tid % 36;
        int h = r / 9, s = (r / 3) % 3, t = r % 3;
        const float* qp = &qk[lb][s * 768 + h * 64];
        const float* kp = &qk[lb][t * 768 + 256 + h * 64];
        float sum = 0.f;
#pragma unroll
        for (int dd = 0; dd < 64; dd++) sum = fmaf(qp[dd], kp[dd], sum);
        at[lb][h][s][t] = sum * 0.125f;
    }
    __syncthreads();

    if (tid < 48) {
        int lb = tid / 12, h = (tid / 3) % 4, s = tid % 3;
        float v0 = at[lb][h][s][0], v1 = at[lb][h][s][1], v2 = at[lb][h][s][2];
        float mx = fmaxf(v0, fmaxf(v1, v2));
        float e0 = expf(v0 - mx), e1 = expf(v1 - mx), e2 = expf(v2 - mx);
        float inv = 1.f / (e0 + e1 + e2);
        at[lb][h][s][0] = e0 * inv; at[lb][h][s][1] = e1 * inv; at[lb][h][s][2] = e2 * inv;
    }
    __syncthreads();

    {
        int j = tid, h = j >> 6;
#pragma unroll
        for (int lb = 0; lb < 4; lb++)
#pragma unroll
            for (int s = 0; s < 3; s++) {
                float o = at[lb][h][s][0] * qk[lb][0 * 768 + 512 + j]
                        + at[lb][h][s][1] * qk[lb][1 * 768 + 512 + j]
                        + at[lb][h][s][2] * qk[lb][2 * 768 + 512 + j];
                ol[lb * 3 + s][j] = o;
            }
    }
    __syncthreads();

    {
        const int txx = tid & 63, lbb = tid >> 6;
        float a0[4] = {0, 0, 0, 0}, a1[4] = {0, 0, 0, 0}, a2[4] = {0, 0, 0, 0};
        for (int k = 0; k < 256; k++) {
            float4 w = *(const float4*)&Wout[(size_t)k * 256 + txx * 4];
            float wv[4] = {w.x, w.y, w.z, w.w};
            float o0 = ol[lbb * 3 + 0][k], o1 = ol[lbb * 3 + 1][k], o2 = ol[lbb * 3 + 2][k];
#pragma unroll
            for (int c = 0; c < 4; c++) {
                a0[c] = fmaf(o0, wv[c], a0[c]);
                a1[c] = fmaf(o1, wv[c], a1[c]);
                a2[c] = fmaf(o2, wv[c], a2[c]);
            }
        }
        float4 bo = *(const float4*)&bout[txx * 4];
        float bc[4] = {bo.x, bo.y, bo.z, bo.w};
        float f[4];
        u16 hq[4], lq[4];
#pragma unroll
        for (int c = 0; c < 4; c++) {
            f[c] = ((a0[c] + bc[c]) + (a1[c] + bc[c]) + (a2[c] + bc[c])) * (1.f / 3.f);
            __hip_bfloat16 hb = __float2bfloat16(f[c]);
            float fh = __bfloat162float(hb);
            __hip_bfloat16 lb2 = __float2bfloat16(f[c] - fh);
            hq[c] = *(u16*)&hb;
            lq[c] = *(u16*)&lb2;
        }
        *(float4*)&fl[lbb][txx * 4] = make_float4(f[0], f[1], f[2], f[3]);
        uint2 hp, lp;
        hp.x = (unsigned)hq[0] | ((unsigned)hq[1] << 16);
        hp.y = (unsigned)hq[2] | ((unsigned)hq[3] << 16);
        lp.x = (unsigned)lq[0] | ((unsigned)lq[1] << 16);
        lp.y = (unsigned)lq[2] | ((unsigned)lq[3] << 16);
        *(uint2*)&Fh[(size_t)(b0 + lbb) * NHID + txx * 4] = hp;
        *(uint2*)&Fl[(size_t)(b0 + lbb) * NHID + txx * 4] = lp;
    }
    __syncthreads();

    {
        int lb = tid >> 6, j = tid & 63;
        float s0 = 0.f, s1 = 0.f;
        for (int k = 0; k < 256; k++) {
            float fv = fl[lb][k];
            s0 = fmaf(fv, W1[(size_t)k * 128 + j], s0);
            s1 = fmaf(fv, W1[(size_t)k * 128 + j + 64], s1);
        }
        h1[lb][j]      = fmaxf(s0 + b1[j], 0.f);
        h1[lb][j + 64] = fmaxf(s1 + b1[j + 64], 0.f);
    }
    __syncthreads();
    if (tid < 4) {
        float s = 0.f;
        for (int j = 0; j < 128; j++) s = fmaf(h1[tid][j], W2[j], s);
        s += b2[0];
        float e = 1.f / (1.f + expf(-s));
        ew[b0 + tid] = fmaxf(e, 1e-8f);
    }
}

// =====================================================================
// K4: logits = F F^T via 3-term bf16 split MFMA GEMM, K' = 768
// =====================================================================
__global__ __launch_bounds__(256) void sim_mfma_kernel(
    const u16* __restrict__ Fh, const u16* __restrict__ Fl, float* __restrict__ C)
{
    __shared__ __align__(16) unsigned char smem[32768];  // A:0..16K, B:16K..32K

    const int tid  = threadIdx.x;
    const int lane = tid & 63;
    const int w    = tid >> 6;
    const int wr   = w >> 1;
    const int wc   = w & 1;
    const int lr   = lane & 15;
    const int lg   = lane >> 4;

    const int orig = blockIdx.x;
    const int wg   = ((orig & 7) << 9) | (orig >> 3);
    const int i0   = (wg >> 6) << 7;
    const int j0   = (wg & 63) << 7;

    const int srow  = lane >> 3;
    const int sslot = (lane & 7) ^ srow;
    const int acol  = sslot * 8;

    f32x4 acc[4][4];
#pragma unroll
    for (int a = 0; a < 4; a++)
#pragma unroll
        for (int b = 0; b < 4; b++) acc[a][b] = (f32x4)0.f;

    for (int kt = 0; kt < 12; kt++) {
        const int seg  = kt >> 2;
        const int kloc = (kt & 3) << 6;
        const u16* Ag = (seg == 1) ? Fl : Fh;
        const u16* Bg = (seg == 2) ? Fl : Fh;

        __syncthreads();
#pragma unroll
        for (int i = 0; i < 4; i++) {
            const int rbase = w * 32 + i * 8;
            GLOAD_LDS16(&Ag[(size_t)(i0 + rbase + srow) * NHID + kloc + acol],
                        smem + rbase * 128);
            GLOAD_LDS16(&Bg[(size_t)(j0 + rbase + srow) * NHID + kloc + acol],
                        smem + 16384 + rbase * 128);
        }
        __syncthreads();

#pragma unroll
        for (int ks = 0; ks < 2; ks++) {
            short8 av[4], bv[4];
            const int slotx = ((ks * 4 + lg) ^ (lr & 7)) * 16;
#pragma unroll
            for (int f = 0; f < 4; f++) {
                av[f] = *(const short8*)(smem + (wr * 64 + f * 16 + lr) * 128 + slotx);
                bv[f] = *(const short8*)(smem + 16384 + (wc * 64 + f * 16 + lr) * 128 + slotx);
            }
#pragma unroll
            for (int fj = 0; fj < 4; fj++)
#pragma unroll
                for (int fi = 0; fi < 4; fi++)
                    acc[fj][fi] = __builtin_amdgcn_mfma_f32_16x16x32_bf16(
                        bv[fj], av[fi], acc[fj][fi], 0, 0, 0);
        }
    }

#pragma unroll
    for (int fj = 0; fj < 4; fj++)
#pragma unroll
        for (int fi = 0; fi < 4; fi++) {
            const int r = i0 + wr * 64 + fi * 16 + lr;
            const int c = j0 + wc * 64 + fj * 16 + lg * 4;
            *(f32x4*)&C[(size_t)r * NB + c] = acc[fj][fi];
        }
}

// =====================================================================
// K5: per-row top-8 via branchless value-only tournament + LDS atomicMin
// owner resolution; sumexp after masking (-INF terms vanish); then
// overwrite row with eye row.
// =====================================================================
__global__ __launch_bounds__(256) void topk_kernel(
    float* __restrict__ logits, float* __restrict__ topv, int* __restrict__ topi)
{
    __shared__ float wv[8][4];   // per-round per-wave max
    __shared__ int   sidx[8];    // per-round winning index (atomicMin)
    __shared__ float red[4];     // sumexp partials
    const int row = blockIdx.x;
    const int tid = threadIdx.x;
    float* L = &logits[(size_t)row * NB];

    if (tid < 8) sidx[tid] = 0x7fffffff;

    float v[32];
#pragma unroll
    for (int q = 0; q < 8; q++) {
        float4 x4 = *(const float4*)&L[(q * 256 + tid) * 4];
        v[q * 4 + 0] = x4.x; v[q * 4 + 1] = x4.y;
        v[q * 4 + 2] = x4.z; v[q * 4 + 3] = x4.w;
    }
    // group-of-4 maxes (value only)
    float g[8];
#pragma unroll
    for (int q = 0; q < 8; q++)
        g[q] = fmaxf(fmaxf(v[q * 4], v[q * 4 + 1]), fmaxf(v[q * 4 + 2], v[q * 4 + 3]));

    __syncthreads();  // covers sidx init

    float rank_v[8]; int rank_i[8];
#pragma unroll
    for (int r = 0; r < 8; r++) {
        // thread max of 8 groups
        float t = fmaxf(fmaxf(fmaxf(g[0], g[1]), fmaxf(g[2], g[3])),
                        fmaxf(fmaxf(g[4], g[5]), fmaxf(g[6], g[7])));
        // wave max
        float wm = t;
#pragma unroll
        for (int off = 1; off < 64; off <<= 1)
            wm = fmaxf(wm, __shfl_xor(wm, off));
        if ((tid & 63) == 0) wv[r][tid >> 6] = wm;
        __syncthreads();
        const float m = fmaxf(fmaxf(wv[r][0], wv[r][1]), fmaxf(wv[r][2], wv[r][3]));
        // owners submit lowest matching global index
        if (t == m) {
            int best = 0x7fffffff;
#pragma unroll
            for (int q = 0; q < 8; q++)
#pragma unroll
                for (int c = 0; c < 4; c++)
                    if (v[q * 4 + c] == m) {
                        int gi = (q * 256 + tid) * 4 + c;
                        best = min(best, gi);
                    }
            atomicMin(&sidx[r], best);
        }
        __syncthreads();
        const int idx = sidx[r];
        rank_v[r] = m; rank_i[r] = idx;
        // owner masks the extracted element, refreshes its group max
        if (((idx >> 2) & 255) == tid) {
            const int q = idx >> 10;
#pragma unroll
            for (int qq = 0; qq < 8; qq++) if (qq == q) {
                const int c = idx & 3;
#pragma unroll
                for (int cc = 0; cc < 4; cc++) if (cc == c)
                    v[qq * 4 + cc] = -INFINITY;
                g[qq] = fmaxf(fmaxf(v[qq * 4], v[qq * 4 + 1]),
                              fmaxf(v[qq * 4 + 2], v[qq * 4 + 3]));
            }
        }
        // no barrier needed: next round uses wv[r+1]/sidx[r+1], only own regs mutated
    }

    // sumexp over remaining (masked -INF terms -> 0); top-8 exps re-added below
    const float mx = rank_v[0];
    float ps = 0.f;
#pragma unroll
    for (int q = 0; q < 32; q++) ps += __expf(v[q] - mx);
#pragma unroll
    for (int off = 1; off < 64; off <<= 1) ps += __shfl_xor(ps, off);
    if ((tid & 63) == 0) red[tid >> 6] = ps;
    __syncthreads();
    if (tid == 0) {
        float er[8];
        float esum = 0.f;
#pragma unroll
        for (int r = 0; r < 8; r++) { er[r] = __expf(rank_v[r] - mx); esum += er[r]; }
        const float inv = 1.f / (red[0] + red[1] + red[2] + red[3] + esum);
#pragma unroll
        for (int r = 0; r < 8; r++) {
            topv[(size_t)row * 8 + r] = er[r] * inv;
            topi[(size_t)row * 8 + r] = rank_i[r];
        }
    }

    // overwrite this row with the identity row (fused former hfill kernel)
    __syncthreads();
#pragma unroll
    for (int q = 0; q < 8; q++) {
        int c4 = (q * 256 + tid) * 4;
        float4 o;
        o.x = (c4 == row)     ? 1.f : 0.f;
        o.y = (c4 + 1 == row) ? 1.f : 0.f;
        o.z = (c4 + 2 == row) ? 1.f : 0.f;
        o.w = (c4 + 3 == row) ? 1.f : 0.f;
        *(float4*)&L[c4] = o;
    }
}

// =====================================================================
// K7: scatter H[idx[i][r], i] = val[i][r]
// =====================================================================
__global__ __launch_bounds__(256) void scatter_kernel(
    const float* __restrict__ topv, const int* __restrict__ topi, float* __restrict__ H)
{
    int t = blockIdx.x * 256 + threadIdx.x;
    int i = t >> 3;
    H[(size_t)topi[t] * NB + i] = topv[t];
}

// =====================================================================
extern "C" void kernel_launch(void* const* d_in, const int* in_sizes, int n_in,
                              void* d_out, int out_size, void* d_ws, size_t ws_size,
                              hipStream_t stream)
{
    const float* x0  = (const float*)d_in[0];
    const float* Wp0 = (const float*)d_in[1];
    const float* bp0 = (const float*)d_in[2];
    const float* g0  = (const float*)d_in[3];
    const float* be0 = (const float*)d_in[4];
    const float* x1  = (const float*)d_in[5];
    const float* Wp1 = (const float*)d_in[6];
    const float* bp1 = (const float*)d_in[7];
    const float* g1  = (const float*)d_in[8];
    const float* be1 = (const float*)d_in[9];
    const float* x2  = (const float*)d_in[10];
    const float* Wp2 = (const float*)d_in[11];
    const float* bp2 = (const float*)d_in[12];
    const float* g2  = (const float*)d_in[13];
    const float* be2 = (const float*)d_in[14];
    const float* Win = (const float*)d_in[15];
    const float* bin = (const float*)d_in[16];
    const float* Wout= (const float*)d_in[17];
    const float* bout= (const float*)d_in[18];
    const float* W1  = (const float*)d_in[19];
    const float* b1  = (const float*)d_in[20];
    const float* W2  = (const float*)d_in[21];
    const float* b2  = (const float*)d_in[22];

    float* out = (float*)d_out;

    float* qkv = out;                    // 24576x768
    float* seq = out + 18874368;         // 24576x256
    u16*   Fh   = (u16*)d_ws;                              // 8192x256 bf16
    u16*   Fl   = (u16*)((char*)d_ws + (4u << 20));        // 8192x256 bf16
    float* topv = (float*)((char*)d_ws + (8u << 20));      // 8192x8
    int*   topi = (int*)((char*)d_ws + (8u << 20) + 262144);
    float* ew   = out + (size_t)NB * NB;

    proj_ln_kernel<<<dim3(256, 3), 256, 0, stream>>>(
        x0, Wp0, bp0, g0, be0, x1, Wp1, bp1, g1, be1, x2, Wp2, bp2, g2, be2, seq);
    qkv_kernel<<<dim3(6, 192), 256, 0, stream>>>(seq, Win, bin, qkv);
    attn_kernel<<<2048, 256, 0, stream>>>(qkv, Wout, bout, W1, b1, W2, b2, Fh, Fl, ew);
    sim_mfma_kernel<<<4096, 256, 0, stream>>>(Fh, Fl, out);
    topk_kernel<<<8192, 256, 0, stream>>>(out, topv, topi);
    scatter_kernel<<<256, 256, 0, stream>>>(topv, topi, out);
}

// Round 4
// 824.853 us; speedup vs baseline: 1.7053x; 1.1761x over previous
//
#include <hip/hip_runtime.h>
#include <hip/hip_bf16.h>
#include <math.h>

#define NB 8192
#define NHID 256

typedef __attribute__((ext_vector_type(8))) short short8;
typedef __attribute__((ext_vector_type(4))) float f32x4;
typedef unsigned short u16;

typedef __attribute__((address_space(3))) unsigned char* as3_u8;
typedef const __attribute__((address_space(1))) unsigned char* as1_cu8;
#define GLOAD_LDS16(g, l) \
    __builtin_amdgcn_global_load_lds((as1_cu8)(g), (as3_u8)(l), 16, 0, 0)

__device__ __forceinline__ void split1(float f, u16& h, u16& l) {
    __hip_bfloat16 hb = __float2bfloat16(f);
    float fh = __bfloat162float(hb);
    __hip_bfloat16 lb = __float2bfloat16(f - fh);
    h = *(u16*)&hb; l = *(u16*)&lb;
}

// =====================================================================
// K0: wconv — transpose + bf16 hi/lo split of Wp0/1/2 and Win.
//   WT  [256][2304]: WT[c][koff_m + k] = Wp_m[k][c]   koff = 0/512/1280
//   WinT[768][256] : WinT[c][k] = Win[k][c]
// =====================================================================
__global__ __launch_bounds__(256) void wconv_kernel(
    const float* __restrict__ Wp0, const float* __restrict__ Wp1,
    const float* __restrict__ Wp2, const float* __restrict__ Win,
    u16* __restrict__ WTh, u16* __restrict__ WTl,
    u16* __restrict__ WinTh, u16* __restrict__ WinTl)
{
    __shared__ float Ts[32][33];
    const int b = blockIdx.x;
    const int tid = threadIdx.x;
    const float* src; u16 *dh, *dl; int W, outstride, outbase, k0, c0;
    if (b < 576) {
        int base, koff;
        const float* wp;
        if (b < 128)      { base = 0;   koff = 0;    wp = Wp0; }
        else if (b < 320) { base = 128; koff = 512;  wp = Wp1; }
        else              { base = 320; koff = 1280; wp = Wp2; }
        int lb = b - base;
        k0 = (lb >> 3) * 32; c0 = (lb & 7) * 32;
        src = wp; W = 256; dh = WTh; dl = WTl; outstride = 2304; outbase = koff;
    } else {
        int lb = b - 576;
        k0 = (lb & 7) * 32; c0 = (lb >> 3) * 32;
        src = Win; W = 768; dh = WinTh; dl = WinTl; outstride = 256; outbase = 0;
    }
    {
        int r = tid >> 3, cq = (tid & 7) * 4;
        float4 v = *(const float4*)&src[(size_t)(k0 + r) * W + c0 + cq];
        Ts[r][cq] = v.x; Ts[r][cq + 1] = v.y; Ts[r][cq + 2] = v.z; Ts[r][cq + 3] = v.w;
    }
    __syncthreads();
    {
        int c = tid >> 3, r4 = (tid & 7) * 4;
        ushort4 h, l;
        split1(Ts[r4 + 0][c], h.x, l.x);
        split1(Ts[r4 + 1][c], h.y, l.y);
        split1(Ts[r4 + 2][c], h.z, l.z);
        split1(Ts[r4 + 3][c], h.w, l.w);
        size_t off = (size_t)(c0 + c) * outstride + outbase + k0 + r4;
        *(ushort4*)&dh[off] = h;
        *(ushort4*)&dl[off] = l;
    }
}

// =====================================================================
// K1: proj_mfma — per-modality Linear -> ReLU -> LayerNorm via 3-term
// bf16-split MFMA. BM=64, BN=256 (full LN row), BK=32, 4 waves, each
// wave = 16 rows x 256 cols (16 frags of 16x16x32, acc 16 x f32x4).
// A-operand = WT rows (out-cols), B-operand = x rows (out-rows):
// D "col"(lane&15) = out-row, D "row"(lg*4+reg) = out-col.
// LDS rows padded to 80B -> 2-way (free) bank pattern on b128 reads.
// Emits seq directly as bf16 hi/lo.
// =====================================================================
__global__ __launch_bounds__(256) void proj_mfma_kernel(
    const float* __restrict__ x0, const float* __restrict__ x1, const float* __restrict__ x2,
    const float* __restrict__ bp0, const float* __restrict__ g0, const float* __restrict__ be0,
    const float* __restrict__ bp1, const float* __restrict__ g1, const float* __restrict__ be1,
    const float* __restrict__ bp2, const float* __restrict__ g2, const float* __restrict__ be2,
    const u16* __restrict__ WTh, const u16* __restrict__ WTl,
    u16* __restrict__ seqh, u16* __restrict__ seql)
{
    // WTh:0 WTl:20480 Xh:40960 Xl:46080  (rows padded to 80B)
    __shared__ __align__(16) unsigned char smem[51200];

    const int m = blockIdx.y;
    const float* x; const float* bp; const float* g; const float* be; int d, koff;
    if (m == 0)      { x = x0; bp = bp0; g = g0; be = be0; d = 512;  koff = 0; }
    else if (m == 1) { x = x1; bp = bp1; g = g1; be = be1; d = 768;  koff = 512; }
    else             { x = x2; bp = bp2; g = g2; be = be2; d = 1024; koff = 1280; }

    const int tid = threadIdx.x;
    const int lane = tid & 63;
    const int w  = tid >> 6;
    const int lr = lane & 15;
    const int lg = lane >> 4;
    const int r0 = blockIdx.x * 64;

    f32x4 acc[16];
#pragma unroll
    for (int nf = 0; nf < 16; nf++) acc[nf] = (f32x4)0.f;

    const int nkt = d >> 5;
    for (int kt = 0; kt < nkt; kt++) {
        const int k0 = kt << 5;
        __syncthreads();
        // stage WT (pre-split): 1024 chunks of 16B per component
#pragma unroll
        for (int i = 0; i < 4; i++) {
            int id = i * 256 + tid;
            int col = id >> 2, ks = (id & 3) * 8;
            size_t go = (size_t)col * 2304 + koff + k0 + ks;
            *(short8*)(smem + col * 80 + ks * 2)         = *(const short8*)&WTh[go];
            *(short8*)(smem + 20480 + col * 80 + ks * 2) = *(const short8*)&WTl[go];
        }
        // stage X with inline split: 512 float4, 2 per thread
#pragma unroll
        for (int i = 0; i < 2; i++) {
            int id = i * 256 + tid;
            int row = id >> 3, kq = (id & 7) * 4;
            float4 v = *(const float4*)&x[(size_t)(r0 + row) * d + k0 + kq];
            ushort4 h, l;
            split1(v.x, h.x, l.x); split1(v.y, h.y, l.y);
            split1(v.z, h.z, l.z); split1(v.w, h.w, l.w);
            *(ushort4*)(smem + 40960 + row * 80 + kq * 2) = h;
            *(ushort4*)(smem + 46080 + row * 80 + kq * 2) = l;
        }
        __syncthreads();

        short8 bvh = *(const short8*)(smem + 40960 + (w * 16 + lr) * 80 + lg * 16);
        short8 bvl = *(const short8*)(smem + 46080 + (w * 16 + lr) * 80 + lg * 16);
#pragma unroll
        for (int nf = 0; nf < 16; nf++) {
            short8 avh = *(const short8*)(smem + (nf * 16 + lr) * 80 + lg * 16);
            short8 avl = *(const short8*)(smem + 20480 + (nf * 16 + lr) * 80 + lg * 16);
            acc[nf] = __builtin_amdgcn_mfma_f32_16x16x32_bf16(avh, bvh, acc[nf], 0, 0, 0);
            acc[nf] = __builtin_amdgcn_mfma_f32_16x16x32_bf16(avl, bvh, acc[nf], 0, 0, 0);
            acc[nf] = __builtin_amdgcn_mfma_f32_16x16x32_bf16(avh, bvl, acc[nf], 0, 0, 0);
        }
    }

    // epilogue: bias + relu + LN (cols spread over lg x nf x reg)
    float s = 0.f, s2 = 0.f;
#pragma unroll
    for (int nf = 0; nf < 16; nf++) {
        float4 bpv = *(const float4*)&bp[nf * 16 + lg * 4];
        float bb[4] = {bpv.x, bpv.y, bpv.z, bpv.w};
#pragma unroll
        for (int r = 0; r < 4; r++) {
            float y = fmaxf(acc[nf][r] + bb[r], 0.f);
            acc[nf][r] = y;
            s += y; s2 += y * y;
        }
    }
    s  += __shfl_xor(s, 16);  s  += __shfl_xor(s, 32);
    s2 += __shfl_xor(s2, 16); s2 += __shfl_xor(s2, 32);
    const float meanv = s * (1.f / 256.f);
    const float inv = 1.f / sqrtf(s2 * (1.f / 256.f) - meanv * meanv + 1e-5f);

    const size_t rb = ((size_t)(r0 + w * 16 + lr) * 3 + m) * 256;
#pragma unroll
    for (int nf = 0; nf < 16; nf++) {
        float4 gv  = *(const float4*)&g[nf * 16 + lg * 4];
        float4 bev = *(const float4*)&be[nf * 16 + lg * 4];
        float gc[4] = {gv.x, gv.y, gv.z, gv.w};
        float bc[4] = {bev.x, bev.y, bev.z, bev.w};
        ushort4 h, l;
        float o0 = (acc[nf][0] - meanv) * inv * gc[0] + bc[0];
        float o1 = (acc[nf][1] - meanv) * inv * gc[1] + bc[1];
        float o2 = (acc[nf][2] - meanv) * inv * gc[2] + bc[2];
        float o3 = (acc[nf][3] - meanv) * inv * gc[3] + bc[3];
        split1(o0, h.x, l.x); split1(o1, h.y, l.y);
        split1(o2, h.z, l.z); split1(o3, h.w, l.w);
        *(ushort4*)&seqh[rb + nf * 16 + lg * 4] = h;
        *(ushort4*)&seql[rb + nf * 16 + lg * 4] = l;
    }
}

// =====================================================================
// K2: qkv_mfma — qkv = seq @ Win + bin via 3-term bf16-split MFMA.
// Same structure as proj_mfma; K=256, col-tiles of 256 (grid.x = 3).
// =====================================================================
__global__ __launch_bounds__(256) void qkv_mfma_kernel(
    const u16* __restrict__ seqh, const u16* __restrict__ seql,
    const u16* __restrict__ WinTh, const u16* __restrict__ WinTl,
    const float* __restrict__ bin, float* __restrict__ qkv)
{
    __shared__ __align__(16) unsigned char smem[51200];
    const int tid = threadIdx.x;
    const int lane = tid & 63;
    const int w  = tid >> 6;
    const int lr = lane & 15;
    const int lg = lane >> 4;
    const int c0 = blockIdx.x << 8;
    const int r0 = blockIdx.y << 6;

    f32x4 acc[16];
#pragma unroll
    for (int nf = 0; nf < 16; nf++) acc[nf] = (f32x4)0.f;

    for (int kt = 0; kt < 8; kt++) {
        const int k0 = kt << 5;
        __syncthreads();
#pragma unroll
        for (int i = 0; i < 4; i++) {
            int id = i * 256 + tid;
            int col = id >> 2, ks = (id & 3) * 8;
            size_t go = (size_t)(c0 + col) * 256 + k0 + ks;
            *(short8*)(smem + col * 80 + ks * 2)         = *(const short8*)&WinTh[go];
            *(short8*)(smem + 20480 + col * 80 + ks * 2) = *(const short8*)&WinTl[go];
        }
        {
            int row = tid >> 2, ks = (tid & 3) * 8;
            size_t go = (size_t)(r0 + row) * 256 + k0 + ks;
            *(short8*)(smem + 40960 + row * 80 + ks * 2) = *(const short8*)&seqh[go];
            *(short8*)(smem + 46080 + row * 80 + ks * 2) = *(const short8*)&seql[go];
        }
        __syncthreads();

        short8 bvh = *(const short8*)(smem + 40960 + (w * 16 + lr) * 80 + lg * 16);
        short8 bvl = *(const short8*)(smem + 46080 + (w * 16 + lr) * 80 + lg * 16);
#pragma unroll
        for (int nf = 0; nf < 16; nf++) {
            short8 avh = *(const short8*)(smem + (nf * 16 + lr) * 80 + lg * 16);
            short8 avl = *(const short8*)(smem + 20480 + (nf * 16 + lr) * 80 + lg * 16);
            acc[nf] = __builtin_amdgcn_mfma_f32_16x16x32_bf16(avh, bvh, acc[nf], 0, 0, 0);
            acc[nf] = __builtin_amdgcn_mfma_f32_16x16x32_bf16(avl, bvh, acc[nf], 0, 0, 0);
            acc[nf] = __builtin_amdgcn_mfma_f32_16x16x32_bf16(avh, bvl, acc[nf], 0, 0, 0);
        }
    }

    const size_t rb = (size_t)(r0 + w * 16 + lr) * 768 + c0;
#pragma unroll
    for (int nf = 0; nf < 16; nf++) {
        float4 bv = *(const float4*)&bin[c0 + nf * 16 + lg * 4];
        float4 o = make_float4(acc[nf][0] + bv.x, acc[nf][1] + bv.y,
                               acc[nf][2] + bv.z, acc[nf][3] + bv.w);
        *(float4*)&qkv[rb + nf * 16 + lg * 4] = o;
    }
}

// =====================================================================
// K3: attention + out-proj + mean + edge MLP; writes Fh/Fl (bf16 split)
// =====================================================================
__global__ __launch_bounds__(256) void attn_kernel(
    const float* __restrict__ qkv, const float* __restrict__ Wout,
    const float* __restrict__ bout, const float* __restrict__ W1,
    const float* __restrict__ b1, const float* __restrict__ W2,
    const float* __restrict__ b2, u16* __restrict__ Fh, u16* __restrict__ Fl,
    float* __restrict__ ew)
{
    __shared__ float qk[4][2304];
    __shared__ float at[4][4][3][3];
    __shared__ float ol[12][256];
    __shared__ float fl[4][256];
    __shared__ float h1[4][128];

    const int tid = threadIdx.x;
    const int b0 = blockIdx.x * 4;

#pragma unroll
    for (int i = 0; i < 9; i++) {
        int f4 = i * 256 + tid;
        int lb = f4 / 576, rem = f4 - lb * 576;
        *(float4*)&qk[lb][rem * 4] =
            *(const float4*)&qkv[(size_t)(b0 + lb) * 2304 + rem * 4];
    }
    __syncthreads();

    if (tid < 144) {
        int lb = tid / 36, r = tid % 36;
        int h = r / 9, s = (r / 3) % 3, t = r % 3;
        const float* qp = &qk[lb][s * 768 + h * 64];
        const float* kp = &qk[lb][t * 768 + 256 + h * 64];
        float sum = 0.f;
#pragma unroll
        for (int dd = 0; dd < 64; dd++) sum = fmaf(qp[dd], kp[dd], sum);
        at[lb][h][s][t] = sum * 0.125f;
    }
    __syncthreads();

    if (tid < 48) {
        int lb = tid / 12, h = (tid / 3) % 4, s = tid % 3;
        float v0 = at[lb][h][s][0], v1 = at[lb][h][s][1], v2 = at[lb][h][s][2];
        float mx = fmaxf(v0, fmaxf(v1, v2));
        float e0 = expf(v0 - mx), e1 = expf(v1 - mx), e2 = expf(v2 - mx);
        float inv = 1.f / (e0 + e1 + e2);
        at[lb][h][s][0] = e0 * inv; at[lb][h][s][1] = e1 * inv; at[lb][h][s][2] = e2 * inv;
    }
    __syncthreads();

    {
        int j = tid, h = j >> 6;
#pragma unroll
        for (int lb = 0; lb < 4; lb++)
#pragma unroll
            for (int s = 0; s < 3; s++) {
                float o = at[lb][h][s][0] * qk[lb][0 * 768 + 512 + j]
                        + at[lb][h][s][1] * qk[lb][1 * 768 + 512 + j]
                        + at[lb][h][s][2] * qk[lb][2 * 768 + 512 + j];
                ol[lb * 3 + s][j] = o;
            }
    }
    __syncthreads();

    {
        const int txx = tid & 63, lbb = tid >> 6;
        float a0[4] = {0, 0, 0, 0}, a1[4] = {0, 0, 0, 0}, a2[4] = {0, 0, 0, 0};
        for (int k = 0; k < 256; k++) {
            float4 w = *(const float4*)&Wout[(size_t)k * 256 + txx * 4];
            float wv[4] = {w.x, w.y, w.z, w.w};
            float o0 = ol[lbb * 3 + 0][k], o1 = ol[lbb * 3 + 1][k], o2 = ol[lbb * 3 + 2][k];
#pragma unroll
            for (int c = 0; c < 4; c++) {
                a0[c] = fmaf(o0, wv[c], a0[c]);
                a1[c] = fmaf(o1, wv[c], a1[c]);
                a2[c] = fmaf(o2, wv[c], a2[c]);
            }
        }
        float4 bo = *(const float4*)&bout[txx * 4];
        float bc[4] = {bo.x, bo.y, bo.z, bo.w};
        float f[4];
        u16 hq[4], lq[4];
#pragma unroll
        for (int c = 0; c < 4; c++) {
            f[c] = ((a0[c] + bc[c]) + (a1[c] + bc[c]) + (a2[c] + bc[c])) * (1.f / 3.f);
            split1(f[c], hq[c], lq[c]);
        }
        *(float4*)&fl[lbb][txx * 4] = make_float4(f[0], f[1], f[2], f[3]);
        uint2 hp, lp;
        hp.x = (unsigned)hq[0] | ((unsigned)hq[1] << 16);
        hp.y = (unsigned)hq[2] | ((unsigned)hq[3] << 16);
        lp.x = (unsigned)lq[0] | ((unsigned)lq[1] << 16);
        lp.y = (unsigned)lq[2] | ((unsigned)lq[3] << 16);
        *(uint2*)&Fh[(size_t)(b0 + lbb) * NHID + txx * 4] = hp;
        *(uint2*)&Fl[(size_t)(b0 + lbb) * NHID + txx * 4] = lp;
    }
    __syncthreads();

    {
        int lb = tid >> 6, j = tid & 63;
        float s0 = 0.f, s1 = 0.f;
        for (int k = 0; k < 256; k++) {
            float fv = fl[lb][k];
            s0 = fmaf(fv, W1[(size_t)k * 128 + j], s0);
            s1 = fmaf(fv, W1[(size_t)k * 128 + j + 64], s1);
        }
        h1[lb][j]      = fmaxf(s0 + b1[j], 0.f);
        h1[lb][j + 64] = fmaxf(s1 + b1[j + 64], 0.f);
    }
    __syncthreads();
    if (tid < 4) {
        float s = 0.f;
        for (int j = 0; j < 128; j++) s = fmaf(h1[tid][j], W2[j], s);
        s += b2[0];
        float e = 1.f / (1.f + expf(-s));
        ew[b0 + tid] = fmaxf(e, 1e-8f);
    }
}

// =====================================================================
// K4: logits = F F^T via 3-term bf16 split MFMA GEMM, K' = 768
// =====================================================================
__global__ __launch_bounds__(256) void sim_mfma_kernel(
    const u16* __restrict__ Fh, const u16* __restrict__ Fl, float* __restrict__ C)
{
    __shared__ __align__(16) unsigned char smem[32768];  // A:0..16K, B:16K..32K

    const int tid  = threadIdx.x;
    const int lane = tid & 63;
    const int w    = tid >> 6;
    const int wr   = w >> 1;
    const int wc   = w & 1;
    const int lr   = lane & 15;
    const int lg   = lane >> 4;

    const int orig = blockIdx.x;
    const int wg   = ((orig & 7) << 9) | (orig >> 3);
    const int i0   = (wg >> 6) << 7;
    const int j0   = (wg & 63) << 7;

    const int srow  = lane >> 3;
    const int sslot = (lane & 7) ^ srow;
    const int acol  = sslot * 8;

    f32x4 acc[4][4];
#pragma unroll
    for (int a = 0; a < 4; a++)
#pragma unroll
        for (int b = 0; b < 4; b++) acc[a][b] = (f32x4)0.f;

    for (int kt = 0; kt < 12; kt++) {
        const int seg  = kt >> 2;
        const int kloc = (kt & 3) << 6;
        const u16* Ag = (seg == 1) ? Fl : Fh;
        const u16* Bg = (seg == 2) ? Fl : Fh;

        __syncthreads();
#pragma unroll
        for (int i = 0; i < 4; i++) {
            const int rbase = w * 32 + i * 8;
            GLOAD_LDS16(&Ag[(size_t)(i0 + rbase + srow) * NHID + kloc + acol],
                        smem + rbase * 128);
            GLOAD_LDS16(&Bg[(size_t)(j0 + rbase + srow) * NHID + kloc + acol],
                        smem + 16384 + rbase * 128);
        }
        __syncthreads();

#pragma unroll
        for (int ks = 0; ks < 2; ks++) {
            short8 av[4], bv[4];
            const int slotx = ((ks * 4 + lg) ^ (lr & 7)) * 16;
#pragma unroll
            for (int f = 0; f < 4; f++) {
                av[f] = *(const short8*)(smem + (wr * 64 + f * 16 + lr) * 128 + slotx);
                bv[f] = *(const short8*)(smem + 16384 + (wc * 64 + f * 16 + lr) * 128 + slotx);
            }
#pragma unroll
            for (int fj = 0; fj < 4; fj++)
#pragma unroll
                for (int fi = 0; fi < 4; fi++)
                    acc[fj][fi] = __builtin_amdgcn_mfma_f32_16x16x32_bf16(
                        bv[fj], av[fi], acc[fj][fi], 0, 0, 0);
        }
    }

#pragma unroll
    for (int fj = 0; fj < 4; fj++)
#pragma unroll
        for (int fi = 0; fi < 4; fi++) {
            const int r = i0 + wr * 64 + fi * 16 + lr;
            const int c = j0 + wc * 64 + fj * 16 + lg * 4;
            *(f32x4*)&C[(size_t)r * NB + c] = acc[fj][fi];
        }
}

// =====================================================================
// K5: per-row top-8 via branchless value-only tournament + LDS atomicMin
// owner resolution; sumexp after masking; then overwrite row with eye row.
// =====================================================================
__global__ __launch_bounds__(256) void topk_kernel(
    float* __restrict__ logits, float* __restrict__ topv, int* __restrict__ topi)
{
    __shared__ float wv[8][4];
    __shared__ int   sidx[8];
    __shared__ float red[4];
    const int row = blockIdx.x;
    const int tid = threadIdx.x;
    float* L = &logits[(size_t)row * NB];

    if (tid < 8) sidx[tid] = 0x7fffffff;

    float v[32];
#pragma unroll
    for (int q = 0; q < 8; q++) {
        float4 x4 = *(const float4*)&L[(q * 256 + tid) * 4];
        v[q * 4 + 0] = x4.x; v[q * 4 + 1] = x4.y;
        v[q * 4 + 2] = x4.z; v[q * 4 + 3] = x4.w;
    }
    float g[8];
#pragma unroll
    for (int q = 0; q < 8; q++)
        g[q] = fmaxf(fmaxf(v[q * 4], v[q * 4 + 1]), fmaxf(v[q * 4 + 2], v[q * 4 + 3]));

    __syncthreads();

    float rank_v[8]; int rank_i[8];
#pragma unroll
    for (int r = 0; r < 8; r++) {
        float t = fmaxf(fmaxf(fmaxf(g[0], g[1]), fmaxf(g[2], g[3])),
                        fmaxf(fmaxf(g[4], g[5]), fmaxf(g[6], g[7])));
        float wm = t;
#pragma unroll
        for (int off = 1; off < 64; off <<= 1)
            wm = fmaxf(wm, __shfl_xor(wm, off));
        if ((tid & 63) == 0) wv[r][tid >> 6] = wm;
        __syncthreads();
        const float m = fmaxf(fmaxf(wv[r][0], wv[r][1]), fmaxf(wv[r][2], wv[r][3]));
        if (t == m) {
            int best = 0x7fffffff;
#pragma unroll
            for (int q = 0; q < 8; q++)
#pragma unroll
                for (int c = 0; c < 4; c++)
                    if (v[q * 4 + c] == m) {
                        int gi = (q * 256 + tid) * 4 + c;
                        best = min(best, gi);
                    }
            atomicMin(&sidx[r], best);
        }
        __syncthreads();
        const int idx = sidx[r];
        rank_v[r] = m; rank_i[r] = idx;
        if (((idx >> 2) & 255) == tid) {
            const int q = idx >> 10;
#pragma unroll
            for (int qq = 0; qq < 8; qq++) if (qq == q) {
                const int c = idx & 3;
#pragma unroll
                for (int cc = 0; cc < 4; cc++) if (cc == c)
                    v[qq * 4 + cc] = -INFINITY;
                g[qq] = fmaxf(fmaxf(v[qq * 4], v[qq * 4 + 1]),
                              fmaxf(v[qq * 4 + 2], v[qq * 4 + 3]));
            }
        }
    }

    const float mx = rank_v[0];
    float ps = 0.f;
#pragma unroll
    for (int q = 0; q < 32; q++) ps += __expf(v[q] - mx);
#pragma unroll
    for (int off = 1; off < 64; off <<= 1) ps += __shfl_xor(ps, off);
    if ((tid & 63) == 0) red[tid >> 6] = ps;
    __syncthreads();
    if (tid == 0) {
        float er[8];
        float esum = 0.f;
#pragma unroll
        for (int r = 0; r < 8; r++) { er[r] = __expf(rank_v[r] - mx); esum += er[r]; }
        const float inv = 1.f / (red[0] + red[1] + red[2] + red[3] + esum);
#pragma unroll
        for (int r = 0; r < 8; r++) {
            topv[(size_t)row * 8 + r] = er[r] * inv;
            topi[(size_t)row * 8 + r] = rank_i[r];
        }
    }

    __syncthreads();
#pragma unroll
    for (int q = 0; q < 8; q++) {
        int c4 = (q * 256 + tid) * 4;
        float4 o;
        o.x = (c4 == row)     ? 1.f : 0.f;
        o.y = (c4 + 1 == row) ? 1.f : 0.f;
        o.z = (c4 + 2 == row) ? 1.f : 0.f;
        o.w = (c4 + 3 == row) ? 1.f : 0.f;
        *(float4*)&L[c4] = o;
    }
}

// =====================================================================
// K7: scatter H[idx[i][r], i] = val[i][r]
// =====================================================================
__global__ __launch_bounds__(256) void scatter_kernel(
    const float* __restrict__ topv, const int* __restrict__ topi, float* __restrict__ H)
{
    int t = blockIdx.x * 256 + threadIdx.x;
    int i = t >> 3;
    H[(size_t)topi[t] * NB + i] = topv[t];
}

// =====================================================================
extern "C" void kernel_launch(void* const* d_in, const int* in_sizes, int n_in,
                              void* d_out, int out_size, void* d_ws, size_t ws_size,
                              hipStream_t stream)
{
    const float* x0  = (const float*)d_in[0];
    const float* Wp0 = (const float*)d_in[1];
    const float* bp0 = (const float*)d_in[2];
    const float* g0  = (const float*)d_in[3];
    const float* be0 = (const float*)d_in[4];
    const float* x1  = (const float*)d_in[5];
    const float* Wp1 = (const float*)d_in[6];
    const float* bp1 = (const float*)d_in[7];
    const float* g1  = (const float*)d_in[8];
    const float* be1 = (const float*)d_in[9];
    const float* x2  = (const float*)d_in[10];
    const float* Wp2 = (const float*)d_in[11];
    const float* bp2 = (const float*)d_in[12];
    const float* g2  = (const float*)d_in[13];
    const float* be2 = (const float*)d_in[14];
    const float* Win = (const float*)d_in[15];
    const float* bin = (const float*)d_in[16];
    const float* Wout= (const float*)d_in[17];
    const float* bout= (const float*)d_in[18];
    const float* W1  = (const float*)d_in[19];
    const float* b1  = (const float*)d_in[20];
    const float* W2  = (const float*)d_in[21];
    const float* b2  = (const float*)d_in[22];

    float* out = (float*)d_out;
    char*  outc = (char*)d_out;

    // scratch inside d_out (all dead before sim's logits overwrite them):
    float* qkv   = out;                              // [0, 75497472) bytes
    u16*   seqh  = (u16*)(outc + 75497472);          // 12.58 MB
    u16*   seql  = (u16*)(outc + 88080384);          // 12.58 MB
    u16*   WTh   = (u16*)(outc + 100663296);         // 1.18 MB
    u16*   WTl   = (u16*)(outc + 101842944);         // 1.18 MB
    u16*   WinTh = (u16*)(outc + 103022592);         // 384 KB
    u16*   WinTl = (u16*)(outc + 103415808);         // 384 KB
    // persistent scratch in d_ws (~8.5 MB):
    u16*   Fh   = (u16*)d_ws;                        // 8192x256 bf16
    u16*   Fl   = (u16*)((char*)d_ws + (4u << 20));  // 8192x256 bf16
    float* topv = (float*)((char*)d_ws + (8u << 20));
    int*   topi = (int*)((char*)d_ws + (8u << 20) + 262144);
    float* ew   = out + (size_t)NB * NB;

    wconv_kernel<<<768, 256, 0, stream>>>(Wp0, Wp1, Wp2, Win, WTh, WTl, WinTh, WinTl);
    proj_mfma_kernel<<<dim3(128, 3), 256, 0, stream>>>(
        x0, x1, x2, bp0, g0, be0, bp1, g1, be1, bp2, g2, be2, WTh, WTl, seqh, seql);
    qkv_mfma_kernel<<<dim3(3, 384), 256, 0, stream>>>(seqh, seql, WinTh, WinTl, bin, qkv);
    attn_kernel<<<2048, 256, 0, stream>>>(qkv, Wout, bout, W1, b1, W2, b2, Fh, Fl, ew);
    sim_mfma_kernel<<<4096, 256, 0, stream>>>(Fh, Fl, out);
    topk_kernel<<<8192, 256, 0, stream>>>(out, topv, topi);
    scatter_kernel<<<256, 256, 0, stream>>>(topv, topi, out);
}

// Round 7
// 804.180 us; speedup vs baseline: 1.7492x; 1.0257x over previous
//
#include <hip/hip_runtime.h>
#include <hip/hip_bf16.h>
#include <math.h>

#define NB 8192
#define NHID 256

typedef __attribute__((ext_vector_type(8))) short short8;
typedef __attribute__((ext_vector_type(4))) float f32x4;
typedef unsigned short u16;

typedef __attribute__((address_space(3))) unsigned char* as3_u8;
typedef const __attribute__((address_space(1))) unsigned char* as1_cu8;
#define GLOAD_LDS16(g, l) \
    __builtin_amdgcn_global_load_lds((as1_cu8)(g), (as3_u8)(l), 16, 0, 0)

__device__ __forceinline__ void split1(float f, u16& h, u16& l) {
    __hip_bfloat16 hb = __float2bfloat16(f);
    float fh = __bfloat162float(hb);
    __hip_bfloat16 lb = __float2bfloat16(f - fh);
    h = *(u16*)&hb; l = *(u16*)&lb;
}

// =====================================================================
// K0: wconv — transpose + bf16 hi/lo split of Wp0/1/2 and Win.
// =====================================================================
__global__ __launch_bounds__(256) void wconv_kernel(
    const float* __restrict__ Wp0, const float* __restrict__ Wp1,
    const float* __restrict__ Wp2, const float* __restrict__ Win,
    u16* __restrict__ WTh, u16* __restrict__ WTl,
    u16* __restrict__ WinTh, u16* __restrict__ WinTl)
{
    __shared__ float Ts[32][33];
    const int b = blockIdx.x;
    const int tid = threadIdx.x;
    const float* src; u16 *dh, *dl; int W, outstride, outbase, k0, c0;
    if (b < 576) {
        int base, koff;
        const float* wp;
        if (b < 128)      { base = 0;   koff = 0;    wp = Wp0; }
        else if (b < 320) { base = 128; koff = 512;  wp = Wp1; }
        else              { base = 320; koff = 1280; wp = Wp2; }
        int lb = b - base;
        k0 = (lb >> 3) * 32; c0 = (lb & 7) * 32;
        src = wp; W = 256; dh = WTh; dl = WTl; outstride = 2304; outbase = koff;
    } else {
        int lb = b - 576;
        k0 = (lb & 7) * 32; c0 = (lb >> 3) * 32;
        src = Win; W = 768; dh = WinTh; dl = WinTl; outstride = 256; outbase = 0;
    }
    {
        int r = tid >> 3, cq = (tid & 7) * 4;
        float4 v = *(const float4*)&src[(size_t)(k0 + r) * W + c0 + cq];
        Ts[r][cq] = v.x; Ts[r][cq + 1] = v.y; Ts[r][cq + 2] = v.z; Ts[r][cq + 3] = v.w;
    }
    __syncthreads();
    {
        int c = tid >> 3, r4 = (tid & 7) * 4;
        ushort4 h, l;
        split1(Ts[r4 + 0][c], h.x, l.x);
        split1(Ts[r4 + 1][c], h.y, l.y);
        split1(Ts[r4 + 2][c], h.z, l.z);
        split1(Ts[r4 + 3][c], h.w, l.w);
        size_t off = (size_t)(c0 + c) * outstride + outbase + k0 + r4;
        *(ushort4*)&dh[off] = h;
        *(ushort4*)&dl[off] = l;
    }
}

// =====================================================================
// K1: proj_mfma — Linear -> ReLU -> LayerNorm via 3-term bf16-split MFMA
// =====================================================================
__global__ __launch_bounds__(256) void proj_mfma_kernel(
    const float* __restrict__ x0, const float* __restrict__ x1, const float* __restrict__ x2,
    const float* __restrict__ bp0, const float* __restrict__ g0, const float* __restrict__ be0,
    const float* __restrict__ bp1, const float* __restrict__ g1, const float* __restrict__ be1,
    const float* __restrict__ bp2, const float* __restrict__ g2, const float* __restrict__ be2,
    const u16* __restrict__ WTh, const u16* __restrict__ WTl,
    u16* __restrict__ seqh, u16* __restrict__ seql)
{
    __shared__ __align__(16) unsigned char smem[51200];

    const int m = blockIdx.y;
    const float* x; const float* bp; const float* g; const float* be; int d, koff;
    if (m == 0)      { x = x0; bp = bp0; g = g0; be = be0; d = 512;  koff = 0; }
    else if (m == 1) { x = x1; bp = bp1; g = g1; be = be1; d = 768;  koff = 512; }
    else             { x = x2; bp = bp2; g = g2; be = be2; d = 1024; koff = 1280; }

    const int tid = threadIdx.x;
    const int lane = tid & 63;
    const int w  = tid >> 6;
    const int lr = lane & 15;
    const int lg = lane >> 4;
    const int r0 = blockIdx.x * 64;

    f32x4 acc[16];
#pragma unroll
    for (int nf = 0; nf < 16; nf++) acc[nf] = (f32x4)0.f;

    const int nkt = d >> 5;
    for (int kt = 0; kt < nkt; kt++) {
        const int k0 = kt << 5;
        __syncthreads();
#pragma unroll
        for (int i = 0; i < 4; i++) {
            int id = i * 256 + tid;
            int col = id >> 2, ks = (id & 3) * 8;
            size_t go = (size_t)col * 2304 + koff + k0 + ks;
            *(short8*)(smem + col * 80 + ks * 2)         = *(const short8*)&WTh[go];
            *(short8*)(smem + 20480 + col * 80 + ks * 2) = *(const short8*)&WTl[go];
        }
#pragma unroll
        for (int i = 0; i < 2; i++) {
            int id = i * 256 + tid;
            int row = id >> 3, kq = (id & 7) * 4;
            float4 v = *(const float4*)&x[(size_t)(r0 + row) * d + k0 + kq];
            ushort4 h, l;
            split1(v.x, h.x, l.x); split1(v.y, h.y, l.y);
            split1(v.z, h.z, l.z); split1(v.w, h.w, l.w);
            *(ushort4*)(smem + 40960 + row * 80 + kq * 2) = h;
            *(ushort4*)(smem + 46080 + row * 80 + kq * 2) = l;
        }
        __syncthreads();

        short8 bvh = *(const short8*)(smem + 40960 + (w * 16 + lr) * 80 + lg * 16);
        short8 bvl = *(const short8*)(smem + 46080 + (w * 16 + lr) * 80 + lg * 16);
#pragma unroll
        for (int nf = 0; nf < 16; nf++) {
            short8 avh = *(const short8*)(smem + (nf * 16 + lr) * 80 + lg * 16);
            short8 avl = *(const short8*)(smem + 20480 + (nf * 16 + lr) * 80 + lg * 16);
            acc[nf] = __builtin_amdgcn_mfma_f32_16x16x32_bf16(avh, bvh, acc[nf], 0, 0, 0);
            acc[nf] = __builtin_amdgcn_mfma_f32_16x16x32_bf16(avl, bvh, acc[nf], 0, 0, 0);
            acc[nf] = __builtin_amdgcn_mfma_f32_16x16x32_bf16(avh, bvl, acc[nf], 0, 0, 0);
        }
    }

    float s = 0.f, s2 = 0.f;
#pragma unroll
    for (int nf = 0; nf < 16; nf++) {
        float4 bpv = *(const float4*)&bp[nf * 16 + lg * 4];
        float bb[4] = {bpv.x, bpv.y, bpv.z, bpv.w};
#pragma unroll
        for (int r = 0; r < 4; r++) {
            float y = fmaxf(acc[nf][r] + bb[r], 0.f);
            acc[nf][r] = y;
            s += y; s2 += y * y;
        }
    }
    s  += __shfl_xor(s, 16);  s  += __shfl_xor(s, 32);
    s2 += __shfl_xor(s2, 16); s2 += __shfl_xor(s2, 32);
    const float meanv = s * (1.f / 256.f);
    const float inv = 1.f / sqrtf(s2 * (1.f / 256.f) - meanv * meanv + 1e-5f);

    const size_t rb = ((size_t)(r0 + w * 16 + lr) * 3 + m) * 256;
#pragma unroll
    for (int nf = 0; nf < 16; nf++) {
        float4 gv  = *(const float4*)&g[nf * 16 + lg * 4];
        float4 bev = *(const float4*)&be[nf * 16 + lg * 4];
        float gc[4] = {gv.x, gv.y, gv.z, gv.w};
        float bc[4] = {bev.x, bev.y, bev.z, bev.w};
        ushort4 h, l;
        float o0 = (acc[nf][0] - meanv) * inv * gc[0] + bc[0];
        float o1 = (acc[nf][1] - meanv) * inv * gc[1] + bc[1];
        float o2 = (acc[nf][2] - meanv) * inv * gc[2] + bc[2];
        float o3 = (acc[nf][3] - meanv) * inv * gc[3] + bc[3];
        split1(o0, h.x, l.x); split1(o1, h.y, l.y);
        split1(o2, h.z, l.z); split1(o3, h.w, l.w);
        *(ushort4*)&seqh[rb + nf * 16 + lg * 4] = h;
        *(ushort4*)&seql[rb + nf * 16 + lg * 4] = l;
    }
}

// =====================================================================
// K2: qkv_mfma — qkv = seq @ Win + bin via 3-term bf16-split MFMA.
// =====================================================================
__global__ __launch_bounds__(256) void qkv_mfma_kernel(
    const u16* __restrict__ seqh, const u16* __restrict__ seql,
    const u16* __restrict__ WinTh, const u16* __restrict__ WinTl,
    const float* __restrict__ bin, float* __restrict__ qkv)
{
    __shared__ __align__(16) unsigned char smem[51200];
    const int tid = threadIdx.x;
    const int lane = tid & 63;
    const int w  = tid >> 6;
    const int lr = lane & 15;
    const int lg = lane >> 4;
    const int c0 = blockIdx.x << 8;
    const int r0 = blockIdx.y << 6;

    f32x4 acc[16];
#pragma unroll
    for (int nf = 0; nf < 16; nf++) acc[nf] = (f32x4)0.f;

    for (int kt = 0; kt < 8; kt++) {
        const int k0 = kt << 5;
        __syncthreads();
#pragma unroll
        for (int i = 0; i < 4; i++) {
            int id = i * 256 + tid;
            int col = id >> 2, ks = (id & 3) * 8;
            size_t go = (size_t)(c0 + col) * 256 + k0 + ks;
            *(short8*)(smem + col * 80 + ks * 2)         = *(const short8*)&WinTh[go];
            *(short8*)(smem + 20480 + col * 80 + ks * 2) = *(const short8*)&WinTl[go];
        }
        {
            int row = tid >> 2, ks = (tid & 3) * 8;
            size_t go = (size_t)(r0 + row) * 256 + k0 + ks;
            *(short8*)(smem + 40960 + row * 80 + ks * 2) = *(const short8*)&seqh[go];
            *(short8*)(smem + 46080 + row * 80 + ks * 2) = *(const short8*)&seql[go];
        }
        __syncthreads();

        short8 bvh = *(const short8*)(smem + 40960 + (w * 16 + lr) * 80 + lg * 16);
        short8 bvl = *(const short8*)(smem + 46080 + (w * 16 + lr) * 80 + lg * 16);
#pragma unroll
        for (int nf = 0; nf < 16; nf++) {
            short8 avh = *(const short8*)(smem + (nf * 16 + lr) * 80 + lg * 16);
            short8 avl = *(const short8*)(smem + 20480 + (nf * 16 + lr) * 80 + lg * 16);
            acc[nf] = __builtin_amdgcn_mfma_f32_16x16x32_bf16(avh, bvh, acc[nf], 0, 0, 0);
            acc[nf] = __builtin_amdgcn_mfma_f32_16x16x32_bf16(avl, bvh, acc[nf], 0, 0, 0);
            acc[nf] = __builtin_amdgcn_mfma_f32_16x16x32_bf16(avh, bvl, acc[nf], 0, 0, 0);
        }
    }

    const size_t rb = (size_t)(r0 + w * 16 + lr) * 768 + c0;
#pragma unroll
    for (int nf = 0; nf < 16; nf++) {
        float4 bv = *(const float4*)&bin[c0 + nf * 16 + lg * 4];
        float4 o = make_float4(acc[nf][0] + bv.x, acc[nf][1] + bv.y,
                               acc[nf][2] + bv.z, acc[nf][3] + bv.w);
        *(float4*)&qkv[rb + nf * 16 + lg * 4] = o;
    }
}

// =====================================================================
// K3: attention + out-proj + mean + edge MLP; writes Fh/Fl (bf16 split)
// =====================================================================
__global__ __launch_bounds__(256) void attn_kernel(
    const float* __restrict__ qkv, const float* __restrict__ Wout,
    const float* __restrict__ bout, const float* __restrict__ W1,
    const float* __restrict__ b1, const float* __restrict__ W2,
    const float* __restrict__ b2, u16* __restrict__ Fh, u16* __restrict__ Fl,
    float* __restrict__ ew)
{
    __shared__ float qk[4][2304];
    __shared__ float at[4][4][3][3];
    __shared__ float ol[12][256];
    __shared__ float fl[4][256];
    __shared__ float h1[4][128];

    const int tid = threadIdx.x;
    const int b0 = blockIdx.x * 4;

#pragma unroll
    for (int i = 0; i < 9; i++) {
        int f4 = i * 256 + tid;
        int lb = f4 / 576, rem = f4 - lb * 576;
        *(float4*)&qk[lb][rem * 4] =
            *(const float4*)&qkv[(size_t)(b0 + lb) * 2304 + rem * 4];
    }
    __syncthreads();

    if (tid < 144) {
        int lb = tid / 36, r = tid % 36;
        int h = r / 9, s = (r / 3) % 3, t = r % 3;
        const float* qp = &qk[lb][s * 768 + h * 64];
        const float* kp = &qk[lb][t * 768 + 256 + h * 64];
        float sum = 0.f;
#pragma unroll
        for (int dd = 0; dd < 64; dd++) sum = fmaf(qp[dd], kp[dd], sum);
        at[lb][h][s][t] = sum * 0.125f;
    }
    __syncthreads();

    if (tid < 48) {
        int lb = tid / 12, h = (tid / 3) % 4, s = tid % 3;
        float v0 = at[lb][h][s][0], v1 = at[lb][h][s][1], v2 = at[lb][h][s][2];
        float mx = fmaxf(v0, fmaxf(v1, v2));
        float e0 = expf(v0 - mx), e1 = expf(v1 - mx), e2 = expf(v2 - mx);
        float inv = 1.f / (e0 + e1 + e2);
        at[lb][h][s][0] = e0 * inv; at[lb][h][s][1] = e1 * inv; at[lb][h][s][2] = e2 * inv;
    }
    __syncthreads();

    {
        int j = tid, h = j >> 6;
#pragma unroll
        for (int lb = 0; lb < 4; lb++)
#pragma unroll
            for (int s = 0; s < 3; s++) {
                float o = at[lb][h][s][0] * qk[lb][0 * 768 + 512 + j]
                        + at[lb][h][s][1] * qk[lb][1 * 768 + 512 + j]
                        + at[lb][h][s][2] * qk[lb][2 * 768 + 512 + j];
                ol[lb * 3 + s][j] = o;
            }
    }
    __syncthreads();

    {
        const int txx = tid & 63, lbb = tid >> 6;
        float a0[4] = {0, 0, 0, 0}, a1[4] = {0, 0, 0, 0}, a2[4] = {0, 0, 0, 0};
        for (int k = 0; k < 256; k++) {
            float4 w = *(const float4*)&Wout[(size_t)k * 256 + txx * 4];
            float wv[4] = {w.x, w.y, w.z, w.w};
            float o0 = ol[lbb * 3 + 0][k], o1 = ol[lbb * 3 + 1][k], o2 = ol[lbb * 3 + 2][k];
#pragma unroll
            for (int c = 0; c < 4; c++) {
                a0[c] = fmaf(o0, wv[c], a0[c]);
                a1[c] = fmaf(o1, wv[c], a1[c]);
                a2[c] = fmaf(o2, wv[c], a2[c]);
            }
        }
        float4 bo = *(const float4*)&bout[txx * 4];
        float bc[4] = {bo.x, bo.y, bo.z, bo.w};
        float f[4];
        u16 hq[4], lq[4];
#pragma unroll
        for (int c = 0; c < 4; c++) {
            f[c] = ((a0[c] + bc[c]) + (a1[c] + bc[c]) + (a2[c] + bc[c])) * (1.f / 3.f);
            split1(f[c], hq[c], lq[c]);
        }
        *(float4*)&fl[lbb][txx * 4] = make_float4(f[0], f[1], f[2], f[3]);
        uint2 hp, lp;
        hp.x = (unsigned)hq[0] | ((unsigned)hq[1] << 16);
        hp.y = (unsigned)hq[2] | ((unsigned)hq[3] << 16);
        lp.x = (unsigned)lq[0] | ((unsigned)lq[1] << 16);
        lp.y = (unsigned)lq[2] | ((unsigned)lq[3] << 16);
        *(uint2*)&Fh[(size_t)(b0 + lbb) * NHID + txx * 4] = hp;
        *(uint2*)&Fl[(size_t)(b0 + lbb) * NHID + txx * 4] = lp;
    }
    __syncthreads();

    {
        int lb = tid >> 6, j = tid & 63;
        float s0 = 0.f, s1 = 0.f;
        for (int k = 0; k < 256; k++) {
            float fv = fl[lb][k];
            s0 = fmaf(fv, W1[(size_t)k * 128 + j], s0);
            s1 = fmaf(fv, W1[(size_t)k * 128 + j + 64], s1);
        }
        h1[lb][j]      = fmaxf(s0 + b1[j], 0.f);
        h1[lb][j + 64] = fmaxf(s1 + b1[j + 64], 0.f);
    }
    __syncthreads();
    if (tid < 4) {
        float s = 0.f;
        for (int j = 0; j < 128; j++) s = fmaf(h1[tid][j], W2[j], s);
        s += b2[0];
        float e = 1.f / (1.f + expf(-s));
        ew[b0 + tid] = fmaxf(e, 1e-8f);
    }
}

// =====================================================================
// K4: logits = F F^T via 3-term bf16 split MFMA GEMM, K' = 768.
// Epilogue repacks acc through LDS so each wave store instruction emits
// full 128B-line-contiguous runs (kills write-allocate refetch), and
// stores nontemporal (logits read exactly once by topk).
// =====================================================================
__global__ __launch_bounds__(256) void sim_mfma_kernel(
    const u16* __restrict__ Fh, const u16* __restrict__ Fl, float* __restrict__ C)
{
    __shared__ __align__(16) unsigned char smem[32768];  // A:0..16K, B:16K..32K

    const int tid  = threadIdx.x;
    const int lane = tid & 63;
    const int w    = tid >> 6;
    const int wr   = w >> 1;
    const int wc   = w & 1;
    const int lr   = lane & 15;
    const int lg   = lane >> 4;

    const int orig = blockIdx.x;
    const int wg   = ((orig & 7) << 9) | (orig >> 3);
    const int i0   = (wg >> 6) << 7;
    const int j0   = (wg & 63) << 7;

    const int srow  = lane >> 3;
    const int sslot = (lane & 7) ^ srow;
    const int acol  = sslot * 8;

    f32x4 acc[4][4];
#pragma unroll
    for (int a = 0; a < 4; a++)
#pragma unroll
        for (int b = 0; b < 4; b++) acc[a][b] = (f32x4)0.f;

    for (int kt = 0; kt < 12; kt++) {
        const int seg  = kt >> 2;
        const int kloc = (kt & 3) << 6;
        const u16* Ag = (seg == 1) ? Fl : Fh;
        const u16* Bg = (seg == 2) ? Fl : Fh;

        __syncthreads();
#pragma unroll
        for (int i = 0; i < 4; i++) {
            const int rbase = w * 32 + i * 8;
            GLOAD_LDS16(&Ag[(size_t)(i0 + rbase + srow) * NHID + kloc + acol],
                        smem + rbase * 128);
            GLOAD_LDS16(&Bg[(size_t)(j0 + rbase + srow) * NHID + kloc + acol],
                        smem + 16384 + rbase * 128);
        }
        __syncthreads();

#pragma unroll
        for (int ks = 0; ks < 2; ks++) {
            short8 av[4], bv[4];
            const int slotx = ((ks * 4 + lg) ^ (lr & 7)) * 16;
#pragma unroll
            for (int f = 0; f < 4; f++) {
                av[f] = *(const short8*)(smem + (wr * 64 + f * 16 + lr) * 128 + slotx);
                bv[f] = *(const short8*)(smem + 16384 + (wc * 64 + f * 16 + lr) * 128 + slotx);
            }
#pragma unroll
            for (int fj = 0; fj < 4; fj++)
#pragma unroll
                for (int fi = 0; fi < 4; fi++)
                    acc[fj][fi] = __builtin_amdgcn_mfma_f32_16x16x32_bf16(
                        bv[fj], av[fi], acc[fj][fi], 0, 0, 0);
        }
    }

    // ---- epilogue: LDS repack -> 128B-contiguous nontemporal stores
    float* rep = (float*)smem;   // [32][132] floats = 16.9 KB
#pragma unroll
    for (int fi = 0; fi < 4; fi++) {
        __syncthreads();
#pragma unroll
        for (int fj = 0; fj < 4; fj++)
            *(f32x4*)&rep[(wr * 16 + lr) * 132 + wc * 64 + fj * 16 + lg * 4] = acc[fj][fi];
        __syncthreads();
#pragma unroll
        for (int i = 0; i < 4; i++) {
            const int id = i * 256 + tid;
            const int rr = id >> 5;      // 0..31 (wr*16 + lr)
            const int ch = id & 31;      // 16B chunk within 128-col row
            f32x4 val = *(const f32x4*)&rep[rr * 132 + ch * 4];
            const int r = i0 + (rr >> 4) * 64 + fi * 16 + (rr & 15);
            __builtin_nontemporal_store(val, (f32x4*)&C[(size_t)r * NB + j0 + ch * 4]);
        }
    }
}

// =====================================================================
// K5: per-row top-8 via branchless value-only tournament + LDS atomicMin
// owner resolution; sumexp after masking; then overwrite row with eye row.
// Nontemporal on the 256MB streams (read-once / write-once).
// =====================================================================
__global__ __launch_bounds__(256) void topk_kernel(
    float* __restrict__ logits, float* __restrict__ topv, int* __restrict__ topi)
{
    __shared__ float wv[8][4];
    __shared__ int   sidx[8];
    __shared__ float red[4];
    const int row = blockIdx.x;
    const int tid = threadIdx.x;
    float* L = &logits[(size_t)row * NB];

    if (tid < 8) sidx[tid] = 0x7fffffff;

    float v[32];
#pragma unroll
    for (int q = 0; q < 8; q++) {
        f32x4 x4 = __builtin_nontemporal_load((const f32x4*)&L[(q * 256 + tid) * 4]);
        v[q * 4 + 0] = x4[0]; v[q * 4 + 1] = x4[1];
        v[q * 4 + 2] = x4[2]; v[q * 4 + 3] = x4[3];
    }
    float g[8];
#pragma unroll
    for (int q = 0; q < 8; q++)
        g[q] = fmaxf(fmaxf(v[q * 4], v[q * 4 + 1]), fmaxf(v[q * 4 + 2], v[q * 4 + 3]));

    __syncthreads();

    float rank_v[8]; int rank_i[8];
#pragma unroll
    for (int r = 0; r < 8; r++) {
        float t = fmaxf(fmaxf(fmaxf(g[0], g[1]), fmaxf(g[2], g[3])),
                        fmaxf(fmaxf(g[4], g[5]), fmaxf(g[6], g[7])));
        float wm = t;
#pragma unroll
        for (int off = 1; off < 64; off <<= 1)
            wm = fmaxf(wm, __shfl_xor(wm, off));
        if ((tid & 63) == 0) wv[r][tid >> 6] = wm;
        __syncthreads();
        const float m = fmaxf(fmaxf(wv[r][0], wv[r][1]), fmaxf(wv[r][2], wv[r][3]));
        if (t == m) {
            int best = 0x7fffffff;
#pragma unroll
            for (int q = 0; q < 8; q++)
#pragma unroll
                for (int c = 0; c < 4; c++)
                    if (v[q * 4 + c] == m) {
                        int gi = (q * 256 + tid) * 4 + c;
                        best = min(best, gi);
                    }
            atomicMin(&sidx[r], best);
        }
        __syncthreads();
        const int idx = sidx[r];
        rank_v[r] = m; rank_i[r] = idx;
        if (((idx >> 2) & 255) == tid) {
            const int q = idx >> 10;
#pragma unroll
            for (int qq = 0; qq < 8; qq++) if (qq == q) {
                const int c = idx & 3;
#pragma unroll
                for (int cc = 0; cc < 4; cc++) if (cc == c)
                    v[qq * 4 + cc] = -INFINITY;
                g[qq] = fmaxf(fmaxf(v[qq * 4], v[qq * 4 + 1]),
                              fmaxf(v[qq * 4 + 2], v[qq * 4 + 3]));
            }
        }
    }

    const float mx = rank_v[0];
    float ps = 0.f;
#pragma unroll
    for (int q = 0; q < 32; q++) ps += __expf(v[q] - mx);
#pragma unroll
    for (int off = 1; off < 64; off <<= 1) ps += __shfl_xor(ps, off);
    if ((tid & 63) == 0) red[tid >> 6] = ps;
    __syncthreads();
    if (tid == 0) {
        float er[8];
        float esum = 0.f;
#pragma unroll
        for (int r = 0; r < 8; r++) { er[r] = __expf(rank_v[r] - mx); esum += er[r]; }
        const float inv = 1.f / (red[0] + red[1] + red[2] + red[3] + esum);
#pragma unroll
        for (int r = 0; r < 8; r++) {
            topv[(size_t)row * 8 + r] = er[r] * inv;
            topi[(size_t)row * 8 + r] = rank_i[r];
        }
    }

    __syncthreads();
#pragma unroll
    for (int q = 0; q < 8; q++) {
        int c4 = (q * 256 + tid) * 4;
        f32x4 o;
        o[0] = (c4 == row)     ? 1.f : 0.f;
        o[1] = (c4 + 1 == row) ? 1.f : 0.f;
        o[2] = (c4 + 2 == row) ? 1.f : 0.f;
        o[3] = (c4 + 3 == row) ? 1.f : 0.f;
        __builtin_nontemporal_store(o, (f32x4*)&L[c4]);
    }
}

// =====================================================================
// K7: scatter H[idx[i][r], i] = val[i][r]
// =====================================================================
__global__ __launch_bounds__(256) void scatter_kernel(
    const float* __restrict__ topv, const int* __restrict__ topi, float* __restrict__ H)
{
    int t = blockIdx.x * 256 + threadIdx.x;
    int i = t >> 3;
    H[(size_t)topi[t] * NB + i] = topv[t];
}

// =====================================================================
extern "C" void kernel_launch(void* const* d_in, const int* in_sizes, int n_in,
                              void* d_out, int out_size, void* d_ws, size_t ws_size,
                              hipStream_t stream)
{
    const float* x0  = (const float*)d_in[0];
    const float* Wp0 = (const float*)d_in[1];
    const float* bp0 = (const float*)d_in[2];
    const float* g0  = (const float*)d_in[3];
    const float* be0 = (const float*)d_in[4];
    const float* x1  = (const float*)d_in[5];
    const float* Wp1 = (const float*)d_in[6];
    const float* bp1 = (const float*)d_in[7];
    const float* g1  = (const float*)d_in[8];
    const float* be1 = (const float*)d_in[9];
    const float* x2  = (const float*)d_in[10];
    const float* Wp2 = (const float*)d_in[11];
    const float* bp2 = (const float*)d_in[12];
    const float* g2  = (const float*)d_in[13];
    const float* be2 = (const float*)d_in[14];
    const float* Win = (const float*)d_in[15];
    const float* bin = (const float*)d_in[16];
    const float* Wout= (const float*)d_in[17];
    const float* bout= (const float*)d_in[18];
    const float* W1  = (const float*)d_in[19];
    const float* b1  = (const float*)d_in[20];
    const float* W2  = (const float*)d_in[21];
    const float* b2  = (const float*)d_in[22];

    float* out = (float*)d_out;
    char*  outc = (char*)d_out;

    // scratch inside d_out (all dead before sim's logits overwrite them):
    float* qkv   = out;                              // [0, 75497472) bytes
    u16*   seqh  = (u16*)(outc + 75497472);
    u16*   seql  = (u16*)(outc + 88080384);
    u16*   WTh   = (u16*)(outc + 100663296);
    u16*   WTl   = (u16*)(outc + 101842944);
    u16*   WinTh = (u16*)(outc + 103022592);
    u16*   WinTl = (u16*)(outc + 103415808);
    // persistent scratch in d_ws (~8.5 MB):
    u16*   Fh   = (u16*)d_ws;
    u16*   Fl   = (u16*)((char*)d_ws + (4u << 20));
    float* topv = (float*)((char*)d_ws + (8u << 20));
    int*   topi = (int*)((char*)d_ws + (8u << 20) + 262144);
    float* ew   = out + (size_t)NB * NB;

    wconv_kernel<<<768, 256, 0, stream>>>(Wp0, Wp1, Wp2, Win, WTh, WTl, WinTh, WinTl);
    proj_mfma_kernel<<<dim3(128, 3), 256, 0, stream>>>(
        x0, x1, x2, bp0, g0, be0, bp1, g1, be1, bp2, g2, be2, WTh, WTl, seqh, seql);
    qkv_mfma_kernel<<<dim3(3, 384), 256, 0, stream>>>(seqh, seql, WinTh, WinTl, bin, qkv);
    attn_kernel<<<2048, 256, 0, stream>>>(qkv, Wout, bout, W1, b1, W2, b2, Fh, Fl, ew);
    sim_mfma_kernel<<<4096, 256, 0, stream>>>(Fh, Fl, out);
    topk_kernel<<<8192, 256, 0, stream>>>(out, topv, topi);
    scatter_kernel<<<256, 256, 0, stream>>>(topv, topi, out);
}